// Round 8
// baseline (295.302 us; speedup 1.0000x reference)
//
#include <hip/hip_runtime.h>

// GAT 2-layer, N=100000 nodes, E=1.6M edges, dims 128->64->64, all fp32.
// Strategy:
//   - s[i] = a[i]·we collapses edge-logit GEMV to per-node scalar (We is [1,64]).
//   - tanh-bounded logits => skip segment_max (exp ratio identical).
//   - CSR build: coarse 128-node-bin counting sort + per-bin in-LDS sort.
//     R9: within-node DETERMINISTIC order (rank-sort by dst).
//   - k_node v2 (R13): register-stationary W frags, pre-converted bf16 hi/lo
//     LDS x-tile; inner loop = ds_read_b128 + MFMA only.
//   - k_aggr v11 (R16): burst-depth experiments (R5 16-deep 42.6us, R7
//     32-deep 46us) prove MLP-per-wave is not the lever; the serial
//     front-end (shfl+exp between bursts) and low wave count are. New
//     bin-strip design: 32-node strips (bins split 4-ways, edge ranges
//     contiguous), per block:
//       P1: w -> LDS (parallel, off the gather path)   P2: denoms (32 thr)
//       P3: wave per 8 nodes, w/c via LDS BROADCAST (zero shfl in loop),
//           1 gather per 4 edges, independent across nodes -> streams.
//     3128 blocks, ~12KB LDS, low VGPR -> occupancy to the 32-wave cap.
//     Fixed index-order sums -> bitwise deterministic.

#define WS_ALIGN 256
#define BIN_SHIFT 7
#define BIN_NODES 128
#define BIN_CAP 2560   // mean bin count 2048, sigma ~44 -> +11.6 sigma margin
#define MAX_BINS 1024
#define EPB 4096       // edges per k_bin block
#define STRIP_CAP 1024 // 32-node strip: mean 512 edges, sigma ~22.6 -> +22 sigma

typedef __attribute__((ext_vector_type(8))) short short8;
typedef __attribute__((ext_vector_type(4))) short short4_t;
typedef __attribute__((ext_vector_type(4))) float f32x4;

__device__ __forceinline__ float fast_tanh(float x) {
  x = fminf(15.f, fmaxf(-15.f, x));
  float e = __expf(2.f * x);
  return (e - 1.f) * __builtin_amdgcn_rcpf(e + 1.f);
}

__device__ __forceinline__ unsigned short f32_to_bf16_rne(float f) {
  unsigned u = __float_as_uint(f);
  unsigned r = u + 0x7fffu + ((u >> 16) & 1u);
  return (unsigned short)(r >> 16);
}

// Split one element of [Wa;Wv] into bf16 hi/lo, FRAGMENT-LINEAR layout:
// i = (((nt*KBLK + kb)*4 + q)*16 + c)*8 + j  <->  W[nt*16+c][kb*32+q*8+j].
__device__ __forceinline__ void prepw_one(const float* __restrict__ Wa,
                                          const float* __restrict__ Wv,
                                          short* __restrict__ Wh, short* __restrict__ Wl,
                                          int K, int i) {
  int KBLK = K / 32;
  int j = i & 7;
  int c = (i >> 3) & 15;
  int q = (i >> 7) & 3;
  int r = i >> 9;  // nt*KBLK + kb
  int nt = r / KBLK, kb = r - nt * KBLK;
  int row = nt * 16 + c;
  int col = kb * 32 + q * 8 + j;
  float f = (row < 64) ? Wa[row * K + col] : Wv[(row - 64) * K + col];
  unsigned u = __float_as_uint(f);
  float hf = __uint_as_float(u & 0xffff0000u);
  Wh[i] = (short)(u >> 16);
  Wl[i] = (short)(__float_as_uint(f - hf) >> 16);
}

// Fused setup: weight prep for both layers + cursor init (one launch).
__global__ void k_setup(const float* __restrict__ W11, const float* __restrict__ W13,
                        short* __restrict__ Wh1, short* __restrict__ Wl1,
                        const float* __restrict__ W21, const float* __restrict__ W23,
                        short* __restrict__ Wh2, short* __restrict__ Wl2,
                        int* __restrict__ cursor, int nb) {
  int i = blockIdx.x * 256 + threadIdx.x;
  if (i < 16384) {
    prepw_one(W11, W13, Wh1, Wl1, 128, i);
  } else if (i < 16384 + 8192) {
    prepw_one(W21, W23, Wh2, Wl2, 64, i - 16384);
  } else {
    int b = i - 24576;
    if (b < nb) cursor[b] = b * BIN_CAP;
  }
}

// Coarse counting-sort of edges into 128-node bins.
__global__ __launch_bounds__(256) void k_bin(const int* __restrict__ src,
                                             const int* __restrict__ dst,
                                             int* __restrict__ cursor,
                                             int* __restrict__ binned, int E, int nb) {
  __shared__ int ssrc[EPB];
  __shared__ int sdst[EPB];
  __shared__ int hist[MAX_BINS];
  __shared__ int base[MAX_BINS];
  int t = threadIdx.x;
  for (int i = t; i < nb; i += 256) hist[i] = 0;
  __syncthreads();
  int e0 = blockIdx.x * EPB;
  for (int i = t; i < EPB; i += 256) {
    int e = e0 + i;
    int sv = -1, dv = 0;
    if (e < E) {
      sv = src[e];
      dv = dst[e];
      atomicAdd(&hist[sv >> BIN_SHIFT], 1);
    }
    ssrc[i] = sv;
    sdst[i] = dv;
  }
  __syncthreads();
  for (int b = t; b < nb; b += 256) {
    int c = hist[b];
    base[b] = c ? atomicAdd(&cursor[b], c) : 0;
    hist[b] = 0;
  }
  __syncthreads();
  for (int i = t; i < EPB; i += 256) {
    int sv = ssrc[i];
    if (sv >= 0) {
      int b = sv >> BIN_SHIFT;
      int r = atomicAdd(&hist[b], 1);
      int pos = base[b] + r;
      if (pos < (b + 1) * BIN_CAP)  // overflow guard (never expected to fire)
        binned[pos] = (sdst[i] << BIN_SHIFT) | (sv & (BIN_NODES - 1));
    }
  }
}

// One block per bin: group by src-within-bin in LDS (counting sort), then
// DETERMINISTIC rank-sort of each node's segment by dst (atomic scatter order
// is launch-dependent; sorted multiset is not). Coalesced write-back of
// dst-only values, emit per-node [rs, re).
__global__ __launch_bounds__(256) void k_sort_bin(int* __restrict__ binned,
                                                  const int* __restrict__ cursor,
                                                  int* __restrict__ rs,
                                                  int* __restrict__ re, int n) {
  __shared__ int ents[BIN_CAP];    // input pk; reused as rank-sorted dst output
  __shared__ int sorted[BIN_CAP];  // node-grouped pk
  __shared__ int hist[BIN_NODES];
  __shared__ int scan[BIN_NODES];
  __shared__ int cur[BIN_NODES];
  int bin = blockIdx.x;
  int t = threadIdx.x;
  int nbase = bin << BIN_SHIFT;
  int cnt = cursor[bin] - bin * BIN_CAP;
  if (cnt > BIN_CAP) cnt = BIN_CAP;
  if (t < BIN_NODES) hist[t] = 0;
  __syncthreads();
  int* bp = binned + (size_t)bin * BIN_CAP;
  for (int i = t; i < cnt; i += 256) {
    int pk = bp[i];
    ents[i] = pk;
    atomicAdd(&hist[pk & (BIN_NODES - 1)], 1);
  }
  __syncthreads();
  if (t < BIN_NODES) scan[t] = hist[t];
  __syncthreads();
  for (int off = 1; off < BIN_NODES; off <<= 1) {
    int add = (t < BIN_NODES && t >= off) ? scan[t - off] : 0;
    __syncthreads();
    if (t < BIN_NODES) scan[t] += add;
    __syncthreads();
  }
  if (t < BIN_NODES) {
    int ex = scan[t] - hist[t];  // exclusive
    cur[t] = ex;
    int node = nbase + t;
    if (node < n) {
      rs[node] = bin * BIN_CAP + ex;
      re[node] = bin * BIN_CAP + ex + hist[t];
    }
  }
  __syncthreads();
  // scatter by node (keep full pk — needed for the rank pass)
  for (int i = t; i < cnt; i += 256) {
    int pk = ents[i];
    int pos = atomicAdd(&cur[pk & (BIN_NODES - 1)], 1);
    sorted[pos] = pk;
  }
  __syncthreads();
  // deterministic rank-sort within each node segment, ascending by dst.
  for (int i = t; i < cnt; i += 256) {
    int pk = sorted[i];
    int node = pk & (BIN_NODES - 1);
    int hi = scan[node];
    int lo = hi - hist[node];
    int r = lo;
    for (int j = lo; j < hi; j++) {
      int pj = sorted[j];
      r += (pj < pk) || (pj == pk && j < i);
    }
    ents[r] = pk >> BIN_SHIFT;  // keep dst only
  }
  __syncthreads();
  for (int i = t; i < cnt; i += 256) bp[i] = ents[i];  // coalesced write-back
}

// MFMA node kernel v2: D[node][0..127] = x[node][:] @ [Wa;Wv]^T, 16x16x32 bf16.
// Block = 256 thr / 4 waves / 64 nodes. Wave w owns output n-tiles {2w,2w+1}
// (32 dims) with W frags REGISTER-STATIONARY (one-time coalesced loads);
// iterates 4 node-subtiles from a pre-converted bf16 hi/lo LDS x-tile
// (+8-short row pad -> only free 2-way conflicts on ds_read_b128).
// Waves 0,1 hold a-dims -> partial s, combined via sP LDS; waves 2,3 write v.
template <int K>
__global__ __launch_bounds__(256) void k_node(
    const float* __restrict__ x, const short* __restrict__ Wh,
    const short* __restrict__ Wl, const float* __restrict__ ba,
    const float* __restrict__ we, const float* __restrict__ bv,
    unsigned short* __restrict__ v_out, float* __restrict__ s_out, int n) {
  constexpr int KBLK = K / 32;
  constexpr int RS = K + 8;  // shorts per LDS row (+16B pad)
  __shared__ short sah[64 * RS];
  __shared__ short sal[64 * RS];
  __shared__ float sP[2][64];
  int t = threadIdx.x;
  int l = t & 63;
  int w = t >> 6;
  int q = l >> 4, c = l & 15;
  int node0b = blockIdx.x * 64;

  // stage x tile: coalesced float4 read -> bf16 hi/lo split -> LDS
  {
    const float4* xg = (const float4*)(x + (size_t)node0b * K);
    constexpr int R4 = K / 4;
#pragma unroll
    for (int it = 0; it < 64 * R4 / 256; it++) {
      int i = it * 256 + t;
      int r = i / R4, k4 = i - r * R4;
      float4 val = (node0b + r < n) ? xg[i] : (float4){0.f, 0.f, 0.f, 0.f};
      float xv[4] = {val.x, val.y, val.z, val.w};
      short4_t hi, lo;
#pragma unroll
      for (int j = 0; j < 4; j++) {
        unsigned u = __float_as_uint(xv[j]);
        hi[j] = (short)(u >> 16);
        float hf = __uint_as_float(u & 0xffff0000u);
        lo[j] = (short)(__float_as_uint(xv[j] - hf) >> 16);
      }
      *(short4_t*)&sah[r * RS + k4 * 4] = hi;
      *(short4_t*)&sal[r * RS + k4 * 4] = lo;
    }
  }

  // one-time W fragment loads (register-stationary), overlap staging wait
  const short8* WhF = (const short8*)Wh;
  const short8* WlF = (const short8*)Wl;
  short8 wfh[2][KBLK], wfl[2][KBLK];
#pragma unroll
  for (int mt = 0; mt < 2; mt++)
#pragma unroll
    for (int kb = 0; kb < KBLK; kb++) {
      size_t f = (size_t)((2 * w + mt) * KBLK + kb) * 64 + l;
      wfh[mt][kb] = WhF[f];
      wfl[mt][kb] = WlF[f];
    }
  __syncthreads();

  f32x4 acc[4][2];
#pragma unroll
  for (int ns = 0; ns < 4; ns++)
#pragma unroll
    for (int mt = 0; mt < 2; mt++) acc[ns][mt] = (f32x4){0.f, 0.f, 0.f, 0.f};

#pragma unroll
  for (int ns = 0; ns < 4; ns++) {
#pragma unroll
    for (int kb = 0; kb < KBLK; kb++) {
      int off = (ns * 16 + c) * RS + kb * 32 + q * 8;
      short8 ah = *(const short8*)&sah[off];
      short8 al = *(const short8*)&sal[off];
#pragma unroll
      for (int mt = 0; mt < 2; mt++) {
        acc[ns][mt] = __builtin_amdgcn_mfma_f32_16x16x32_bf16(ah, wfh[mt][kb], acc[ns][mt], 0, 0, 0);
        acc[ns][mt] = __builtin_amdgcn_mfma_f32_16x16x32_bf16(ah, wfl[mt][kb], acc[ns][mt], 0, 0, 0);
        acc[ns][mt] = __builtin_amdgcn_mfma_f32_16x16x32_bf16(al, wfh[mt][kb], acc[ns][mt], 0, 0, 0);
      }
    }
  }

  // ---- epilogue ----
  if (w < 2) {
    // a-dims: partial s over this wave's 32 dims
    float bav0 = ba[w * 32 + c], wev0 = we[w * 32 + c];
    float bav1 = ba[w * 32 + 16 + c], wev1 = we[w * 32 + 16 + c];
#pragma unroll
    for (int ns = 0; ns < 4; ns++) {
#pragma unroll
      for (int r = 0; r < 4; r++) {
        float pv = fast_tanh(acc[ns][0][r] + bav0) * wev0 +
                   fast_tanh(acc[ns][1][r] + bav1) * wev1;
#pragma unroll
        for (int mm = 1; mm < 16; mm <<= 1) pv += __shfl_xor(pv, mm, 64);
        if (c == 0) sP[w][ns * 16 + q * 4 + r] = pv;
      }
    }
  } else {
    // v-dims: write bf16 v
    int wv = w - 2;
    float bvv0 = bv[wv * 32 + c], bvv1 = bv[wv * 32 + 16 + c];
#pragma unroll
    for (int ns = 0; ns < 4; ns++) {
#pragma unroll
      for (int r = 0; r < 4; r++) {
        int node = node0b + ns * 16 + q * 4 + r;
        if (node < n) {
          v_out[(size_t)node * 64 + wv * 32 + c] =
              f32_to_bf16_rne(fast_tanh(acc[ns][0][r] + bvv0));
          v_out[(size_t)node * 64 + wv * 32 + 16 + c] =
              f32_to_bf16_rne(fast_tanh(acc[ns][1][r] + bvv1));
        }
      }
    }
  }
  __syncthreads();
  if (t < 64) {
    int node = node0b + t;
    if (node < n) s_out[node] = sP[0][t] + sP[1][t];
  }
}

// k_aggr v11: bin-strip block kernel. Block = 32-node strip (bin/4); strips
// have contiguous edge ranges in `binned`. Phases (barrier-separated):
//   P0: strip meta (rs/re -> LDS, strip-local)
//   P0b: per-edge owner's s broadcast into srw (32 thr, serial fills)
//   P1: all 256 thr: cols coalesced -> cle; w = exp(tanh(srow+s[c]+be)) -> wle
//   P2: per-node denominators (32 thr, serial edge order, deterministic)
//   P3: wave per 8 nodes: per iter 4 edges of one node, w/c via LDS broadcast
//       (no shfl), gathers independent across iters AND nodes -> streams.
// n=100000 is an exact multiple of 32 -> strips fully valid or fully past n.
__global__ __launch_bounds__(256) void k_aggr(const int* __restrict__ rs,
                                              const int* __restrict__ re,
                                              const int* __restrict__ col,
                                              const float* __restrict__ s,
                                              const float* __restrict__ be_p,
                                              const unsigned short* __restrict__ v,
                                              float* __restrict__ out, int n) {
  __shared__ float wle[STRIP_CAP];
  __shared__ int cle[STRIP_CAP];
  __shared__ float srw[STRIP_CAP];
  __shared__ int lrs[32];
  __shared__ int lre[32];
  __shared__ float sden[32];
  int t = threadIdx.x;
  int strip0 = blockIdx.x * 32;
  if (strip0 >= n) return;

  int estart = rs[strip0];
  int ecnt = re[strip0 + 31] - estart;
  if (ecnt > STRIP_CAP) ecnt = STRIP_CAP;

  if (t < 32) {
    int a = rs[strip0 + t] - estart;
    int b = re[strip0 + t] - estart;
    if (a > STRIP_CAP) a = STRIP_CAP;
    if (b > STRIP_CAP) b = STRIP_CAP;
    lrs[t] = a;
    lre[t] = b;
  }
  __syncthreads();
  if (t < 32) {
    float sv = s[strip0 + t];
    for (int i = lrs[t]; i < lre[t]; i++) srw[i] = sv;
  }
  __syncthreads();
  float be = be_p[0];
  for (int i = t; i < ecnt; i += 256) {
    int c = col[estart + i];
    cle[i] = c;
    wle[i] = __expf(fast_tanh(srw[i] + s[c] + be));
  }
  __syncthreads();
  if (t < 32) {
    float d = 0.f;
    for (int i = lrs[t]; i < lre[t]; i++) d += wle[i];
    sden[t] = d;
  }
  __syncthreads();

  int wv_ = t >> 6;
  int l = t & 63;
  int es = l >> 4;  // edge sub-slot 0..3
  int g = l & 15;   // dim group: dims g*4 .. g*4+3
#pragma unroll 1
  for (int j = 0; j < 8; j++) {
    int nd = wv_ * 8 + j;
    int b0 = lrs[nd];
    int m = lre[nd] - b0;
    float a0 = 0.f, a1 = 0.f, a2 = 0.f, a3 = 0.f;
    for (int k = es; k < m; k += 4) {
      int idx = b0 + k;
      int c = cle[idx];     // LDS broadcast within quarter
      float wj = wle[idx];  // LDS broadcast within quarter
      uint2 pk = *(const uint2*)(v + ((size_t)c << 6) + (g << 2));
      a0 = fmaf(wj, __uint_as_float(pk.x << 16), a0);
      a1 = fmaf(wj, __uint_as_float(pk.x & 0xffff0000u), a1);
      a2 = fmaf(wj, __uint_as_float(pk.y << 16), a2);
      a3 = fmaf(wj, __uint_as_float(pk.y & 0xffff0000u), a3);
    }
    // fold the 4 edge-sub partials (fixed tree -> deterministic)
#pragma unroll
    for (int mm = 16; mm < 64; mm <<= 1) {
      a0 += __shfl_xor(a0, mm, 64);
      a1 += __shfl_xor(a1, mm, 64);
      a2 += __shfl_xor(a2, mm, 64);
      a3 += __shfl_xor(a3, mm, 64);
    }
    float inv = __builtin_amdgcn_rcpf(sden[nd]);
    float o0 = a0 * inv, o1 = a1 * inv, o2 = a2 * inv, o3 = a3 * inv;
    // row stats: values es-replicated -> reduce over g only (4 levels)
    float t0 = o0 + o1 + o2 + o3;
    float t1 = o0 * o0 + o1 * o1 + o2 * o2 + o3 * o3;
#pragma unroll
    for (int mm = 1; mm < 16; mm <<= 1) {
      t0 += __shfl_xor(t0, mm, 64);
      t1 += __shfl_xor(t1, mm, 64);
    }
    float var = (t1 - t0 * t0 * (1.0f / 64.f)) * (1.0f / 63.f);
    float isd = __builtin_amdgcn_rsqf(var);
    if (es == 0) {
      float4 r = {o0 * isd, o1 * isd, o2 * isd, o3 * isd};
      *(float4*)&out[(size_t)(strip0 + nd) * 64 + (g << 2)] = r;
    }
  }
}

extern "C" void kernel_launch(void* const* d_in, const int* in_sizes, int n_in,
                              void* d_out, int out_size, void* d_ws, size_t ws_size,
                              hipStream_t stream) {
  const float* h = (const float*)d_in[0];
  const int* ei = (const int*)d_in[1];
  const float* W11 = (const float*)d_in[2];
  const float* b11 = (const float*)d_in[3];
  const float* W12 = (const float*)d_in[4];  // [1,64] -> 64-vec
  const float* b12 = (const float*)d_in[5];
  const float* W13 = (const float*)d_in[6];
  const float* b13 = (const float*)d_in[7];
  const float* W21 = (const float*)d_in[8];
  const float* b21 = (const float*)d_in[9];
  const float* W22 = (const float*)d_in[10];
  const float* b22 = (const float*)d_in[11];
  const float* W23 = (const float*)d_in[12];
  const float* b23 = (const float*)d_in[13];

  const int N = in_sizes[0] / 128;  // 100000
  const int E = in_sizes[1] / 2;    // 1600000
  const int* src = ei;
  const int* dst = ei + E;
  const int NB = (N + BIN_NODES - 1) >> BIN_SHIFT;  // 782

  // workspace carve-up (~48 MB)
  char* p = (char*)d_ws;
  auto alloc = [&](size_t bytes) -> void* {
    void* r = (void*)p;
    p += (bytes + WS_ALIGN - 1) / WS_ALIGN * WS_ALIGN;
    return r;
  };
  int* cursor = (int*)alloc((size_t)NB * 4);
  int* binned = (int*)alloc((size_t)NB * BIN_CAP * 4);  // 8.0MB
  int* rsb = (int*)alloc((size_t)N * 4);
  int* reb = (int*)alloc((size_t)N * 4);
  float* sbuf = (float*)alloc((size_t)N * 4);
  unsigned short* vbuf = (unsigned short*)alloc((size_t)N * 64 * 2);  // bf16
  float* out1 = (float*)alloc((size_t)N * 64 * 4);
  short* Wh1 = (short*)alloc(128 * 128 * 2);
  short* Wl1 = (short*)alloc(128 * 128 * 2);
  short* Wh2 = (short*)alloc(128 * 64 * 2);
  short* Wl2 = (short*)alloc(128 * 64 * 2);

  // ---- setup: weight prep (both layers) + cursor init, one launch ----
  k_setup<<<(24576 + NB + 255) / 256, 256, 0, stream>>>(
      W11, W13, Wh1, Wl1, W21, W23, Wh2, Wl2, cursor, NB);

  // ---- CSR build via bin sort (reused by both layers) ----
  k_bin<<<(E + EPB - 1) / EPB, 256, 0, stream>>>(src, dst, cursor, binned, E, NB);
  k_sort_bin<<<NB, 256, 0, stream>>>(binned, cursor, rsb, reb, N);

  // ---- layer 1 (K=128) ----
  k_node<128><<<(N + 63) / 64, 256, 0, stream>>>(h, Wh1, Wl1, b11, W12, b13, vbuf, sbuf, N);
  k_aggr<<<NB * 4, 256, 0, stream>>>(rsb, reb, binned, sbuf, b12, vbuf, out1, N);

  // ---- layer 2 (K=64) ----
  k_node<64><<<(N + 63) / 64, 256, 0, stream>>>(out1, Wh2, Wl2, b21, W22, b23, vbuf, sbuf, N);
  k_aggr<<<NB * 4, 256, 0, stream>>>(rsb, reb, binned, sbuf, b22, vbuf, (float*)d_out, N);
}

// Round 10
// 281.639 us; speedup vs baseline: 1.0485x; 1.0485x over previous
//
#include <hip/hip_runtime.h>

// GAT 2-layer, N=100000 nodes, E=1.6M edges, dims 128->64->64, all fp32.
// Strategy:
//   - s[i] = a[i]·we collapses edge-logit GEMV to per-node scalar (We is [1,64]).
//   - tanh-bounded logits => skip segment_max (exp ratio identical).
//   - CSR build: coarse 128-node-bin counting sort + per-bin in-LDS sort.
//     R9: within-node DETERMINISTIC order (rank-sort by dst).
//   - k_node v2 (R13): register-stationary W frags, pre-converted bf16 hi/lo
//     LDS x-tile; inner loop = ds_read_b128 + MFMA only.
//   - k_aggr v7 (R13) REVERTED as the proven best (42.6us). R6 32-burst w/
//     launch-bounds clamp spilled (53us); R7 unclamped 32-burst 46us; R8
//     bin-strip 53.7us (VGPR starved to 16 -> no outstanding gathers).
//     Lesson: the compiler's own schedule at ~56 VGPR beats explicit depth.
//   - R17/R18: AGGR_BLOCKS 2048 -> 1563. 6252 waves x 4 groups = 25008 ~=
//     ngroups exactly; kills the 31% straggler tail (waves drawing 4 of avg
//     3.05). Wave->group map pure function of wid -> bitwise deterministic.
//     (R9 run was lost to container failure; resubmitted unchanged.)

#define WS_ALIGN 256
#define BIN_SHIFT 7
#define BIN_NODES 128
#define BIN_CAP 2560   // mean bin count 2048, sigma ~44 -> +11.6 sigma margin
#define MAX_BINS 1024
#define EPB 4096       // edges per k_bin block
#define AGGR_BLOCKS 1563

typedef __attribute__((ext_vector_type(8))) short short8;
typedef __attribute__((ext_vector_type(4))) short short4_t;
typedef __attribute__((ext_vector_type(4))) float f32x4;

__device__ __forceinline__ float fast_tanh(float x) {
  x = fminf(15.f, fmaxf(-15.f, x));
  float e = __expf(2.f * x);
  return (e - 1.f) * __builtin_amdgcn_rcpf(e + 1.f);
}

__device__ __forceinline__ unsigned short f32_to_bf16_rne(float f) {
  unsigned u = __float_as_uint(f);
  unsigned r = u + 0x7fffu + ((u >> 16) & 1u);
  return (unsigned short)(r >> 16);
}

// Split one element of [Wa;Wv] into bf16 hi/lo, FRAGMENT-LINEAR layout:
// i = (((nt*KBLK + kb)*4 + q)*16 + c)*8 + j  <->  W[nt*16+c][kb*32+q*8+j].
__device__ __forceinline__ void prepw_one(const float* __restrict__ Wa,
                                          const float* __restrict__ Wv,
                                          short* __restrict__ Wh, short* __restrict__ Wl,
                                          int K, int i) {
  int KBLK = K / 32;
  int j = i & 7;
  int c = (i >> 3) & 15;
  int q = (i >> 7) & 3;
  int r = i >> 9;  // nt*KBLK + kb
  int nt = r / KBLK, kb = r - nt * KBLK;
  int row = nt * 16 + c;
  int col = kb * 32 + q * 8 + j;
  float f = (row < 64) ? Wa[row * K + col] : Wv[(row - 64) * K + col];
  unsigned u = __float_as_uint(f);
  float hf = __uint_as_float(u & 0xffff0000u);
  Wh[i] = (short)(u >> 16);
  Wl[i] = (short)(__float_as_uint(f - hf) >> 16);
}

// Fused setup: weight prep for both layers + cursor init (one launch).
__global__ void k_setup(const float* __restrict__ W11, const float* __restrict__ W13,
                        short* __restrict__ Wh1, short* __restrict__ Wl1,
                        const float* __restrict__ W21, const float* __restrict__ W23,
                        short* __restrict__ Wh2, short* __restrict__ Wl2,
                        int* __restrict__ cursor, int nb) {
  int i = blockIdx.x * 256 + threadIdx.x;
  if (i < 16384) {
    prepw_one(W11, W13, Wh1, Wl1, 128, i);
  } else if (i < 16384 + 8192) {
    prepw_one(W21, W23, Wh2, Wl2, 64, i - 16384);
  } else {
    int b = i - 24576;
    if (b < nb) cursor[b] = b * BIN_CAP;
  }
}

// Coarse counting-sort of edges into 128-node bins.
__global__ __launch_bounds__(256) void k_bin(const int* __restrict__ src,
                                             const int* __restrict__ dst,
                                             int* __restrict__ cursor,
                                             int* __restrict__ binned, int E, int nb) {
  __shared__ int ssrc[EPB];
  __shared__ int sdst[EPB];
  __shared__ int hist[MAX_BINS];
  __shared__ int base[MAX_BINS];
  int t = threadIdx.x;
  for (int i = t; i < nb; i += 256) hist[i] = 0;
  __syncthreads();
  int e0 = blockIdx.x * EPB;
  for (int i = t; i < EPB; i += 256) {
    int e = e0 + i;
    int sv = -1, dv = 0;
    if (e < E) {
      sv = src[e];
      dv = dst[e];
      atomicAdd(&hist[sv >> BIN_SHIFT], 1);
    }
    ssrc[i] = sv;
    sdst[i] = dv;
  }
  __syncthreads();
  for (int b = t; b < nb; b += 256) {
    int c = hist[b];
    base[b] = c ? atomicAdd(&cursor[b], c) : 0;
    hist[b] = 0;
  }
  __syncthreads();
  for (int i = t; i < EPB; i += 256) {
    int sv = ssrc[i];
    if (sv >= 0) {
      int b = sv >> BIN_SHIFT;
      int r = atomicAdd(&hist[b], 1);
      int pos = base[b] + r;
      if (pos < (b + 1) * BIN_CAP)  // overflow guard (never expected to fire)
        binned[pos] = (sdst[i] << BIN_SHIFT) | (sv & (BIN_NODES - 1));
    }
  }
}

// One block per bin: group by src-within-bin in LDS (counting sort), then
// DETERMINISTIC rank-sort of each node's segment by dst (atomic scatter order
// is launch-dependent; sorted multiset is not). Coalesced write-back of
// dst-only values, emit per-node [rs, re).
__global__ __launch_bounds__(256) void k_sort_bin(int* __restrict__ binned,
                                                  const int* __restrict__ cursor,
                                                  int* __restrict__ rs,
                                                  int* __restrict__ re, int n) {
  __shared__ int ents[BIN_CAP];    // input pk; reused as rank-sorted dst output
  __shared__ int sorted[BIN_CAP];  // node-grouped pk
  __shared__ int hist[BIN_NODES];
  __shared__ int scan[BIN_NODES];
  __shared__ int cur[BIN_NODES];
  int bin = blockIdx.x;
  int t = threadIdx.x;
  int nbase = bin << BIN_SHIFT;
  int cnt = cursor[bin] - bin * BIN_CAP;
  if (cnt > BIN_CAP) cnt = BIN_CAP;
  if (t < BIN_NODES) hist[t] = 0;
  __syncthreads();
  int* bp = binned + (size_t)bin * BIN_CAP;
  for (int i = t; i < cnt; i += 256) {
    int pk = bp[i];
    ents[i] = pk;
    atomicAdd(&hist[pk & (BIN_NODES - 1)], 1);
  }
  __syncthreads();
  if (t < BIN_NODES) scan[t] = hist[t];
  __syncthreads();
  for (int off = 1; off < BIN_NODES; off <<= 1) {
    int add = (t < BIN_NODES && t >= off) ? scan[t - off] : 0;
    __syncthreads();
    if (t < BIN_NODES) scan[t] += add;
    __syncthreads();
  }
  if (t < BIN_NODES) {
    int ex = scan[t] - hist[t];  // exclusive
    cur[t] = ex;
    int node = nbase + t;
    if (node < n) {
      rs[node] = bin * BIN_CAP + ex;
      re[node] = bin * BIN_CAP + ex + hist[t];
    }
  }
  __syncthreads();
  // scatter by node (keep full pk — needed for the rank pass)
  for (int i = t; i < cnt; i += 256) {
    int pk = ents[i];
    int pos = atomicAdd(&cur[pk & (BIN_NODES - 1)], 1);
    sorted[pos] = pk;
  }
  __syncthreads();
  // deterministic rank-sort within each node segment, ascending by dst.
  for (int i = t; i < cnt; i += 256) {
    int pk = sorted[i];
    int node = pk & (BIN_NODES - 1);
    int hi = scan[node];
    int lo = hi - hist[node];
    int r = lo;
    for (int j = lo; j < hi; j++) {
      int pj = sorted[j];
      r += (pj < pk) || (pj == pk && j < i);
    }
    ents[r] = pk >> BIN_SHIFT;  // keep dst only
  }
  __syncthreads();
  for (int i = t; i < cnt; i += 256) bp[i] = ents[i];  // coalesced write-back
}

// MFMA node kernel v2: D[node][0..127] = x[node][:] @ [Wa;Wv]^T, 16x16x32 bf16.
// Block = 256 thr / 4 waves / 64 nodes. Wave w owns output n-tiles {2w,2w+1}
// (32 dims) with W frags REGISTER-STATIONARY (one-time coalesced loads);
// iterates 4 node-subtiles from a pre-converted bf16 hi/lo LDS x-tile
// (+8-short row pad -> only free 2-way conflicts on ds_read_b128).
// Waves 0,1 hold a-dims -> partial s, combined via sP LDS; waves 2,3 write v.
template <int K>
__global__ __launch_bounds__(256) void k_node(
    const float* __restrict__ x, const short* __restrict__ Wh,
    const short* __restrict__ Wl, const float* __restrict__ ba,
    const float* __restrict__ we, const float* __restrict__ bv,
    unsigned short* __restrict__ v_out, float* __restrict__ s_out, int n) {
  constexpr int KBLK = K / 32;
  constexpr int RS = K + 8;  // shorts per LDS row (+16B pad)
  __shared__ short sah[64 * RS];
  __shared__ short sal[64 * RS];
  __shared__ float sP[2][64];
  int t = threadIdx.x;
  int l = t & 63;
  int w = t >> 6;
  int q = l >> 4, c = l & 15;
  int node0b = blockIdx.x * 64;

  // stage x tile: coalesced float4 read -> bf16 hi/lo split -> LDS
  {
    const float4* xg = (const float4*)(x + (size_t)node0b * K);
    constexpr int R4 = K / 4;
#pragma unroll
    for (int it = 0; it < 64 * R4 / 256; it++) {
      int i = it * 256 + t;
      int r = i / R4, k4 = i - r * R4;
      float4 val = (node0b + r < n) ? xg[i] : (float4){0.f, 0.f, 0.f, 0.f};
      float xv[4] = {val.x, val.y, val.z, val.w};
      short4_t hi, lo;
#pragma unroll
      for (int j = 0; j < 4; j++) {
        unsigned u = __float_as_uint(xv[j]);
        hi[j] = (short)(u >> 16);
        float hf = __uint_as_float(u & 0xffff0000u);
        lo[j] = (short)(__float_as_uint(xv[j] - hf) >> 16);
      }
      *(short4_t*)&sah[r * RS + k4 * 4] = hi;
      *(short4_t*)&sal[r * RS + k4 * 4] = lo;
    }
  }

  // one-time W fragment loads (register-stationary), overlap staging wait
  const short8* WhF = (const short8*)Wh;
  const short8* WlF = (const short8*)Wl;
  short8 wfh[2][KBLK], wfl[2][KBLK];
#pragma unroll
  for (int mt = 0; mt < 2; mt++)
#pragma unroll
    for (int kb = 0; kb < KBLK; kb++) {
      size_t f = (size_t)((2 * w + mt) * KBLK + kb) * 64 + l;
      wfh[mt][kb] = WhF[f];
      wfl[mt][kb] = WlF[f];
    }
  __syncthreads();

  f32x4 acc[4][2];
#pragma unroll
  for (int ns = 0; ns < 4; ns++)
#pragma unroll
    for (int mt = 0; mt < 2; mt++) acc[ns][mt] = (f32x4){0.f, 0.f, 0.f, 0.f};

#pragma unroll
  for (int ns = 0; ns < 4; ns++) {
#pragma unroll
    for (int kb = 0; kb < KBLK; kb++) {
      int off = (ns * 16 + c) * RS + kb * 32 + q * 8;
      short8 ah = *(const short8*)&sah[off];
      short8 al = *(const short8*)&sal[off];
#pragma unroll
      for (int mt = 0; mt < 2; mt++) {
        acc[ns][mt] = __builtin_amdgcn_mfma_f32_16x16x32_bf16(ah, wfh[mt][kb], acc[ns][mt], 0, 0, 0);
        acc[ns][mt] = __builtin_amdgcn_mfma_f32_16x16x32_bf16(ah, wfl[mt][kb], acc[ns][mt], 0, 0, 0);
        acc[ns][mt] = __builtin_amdgcn_mfma_f32_16x16x32_bf16(al, wfh[mt][kb], acc[ns][mt], 0, 0, 0);
      }
    }
  }

  // ---- epilogue ----
  if (w < 2) {
    // a-dims: partial s over this wave's 32 dims
    float bav0 = ba[w * 32 + c], wev0 = we[w * 32 + c];
    float bav1 = ba[w * 32 + 16 + c], wev1 = we[w * 32 + 16 + c];
#pragma unroll
    for (int ns = 0; ns < 4; ns++) {
#pragma unroll
      for (int r = 0; r < 4; r++) {
        float pv = fast_tanh(acc[ns][0][r] + bav0) * wev0 +
                   fast_tanh(acc[ns][1][r] + bav1) * wev1;
#pragma unroll
        for (int mm = 1; mm < 16; mm <<= 1) pv += __shfl_xor(pv, mm, 64);
        if (c == 0) sP[w][ns * 16 + q * 4 + r] = pv;
      }
    }
  } else {
    // v-dims: write bf16 v
    int wv = w - 2;
    float bvv0 = bv[wv * 32 + c], bvv1 = bv[wv * 32 + 16 + c];
#pragma unroll
    for (int ns = 0; ns < 4; ns++) {
#pragma unroll
      for (int r = 0; r < 4; r++) {
        int node = node0b + ns * 16 + q * 4 + r;
        if (node < n) {
          v_out[(size_t)node * 64 + wv * 32 + c] =
              f32_to_bf16_rne(fast_tanh(acc[ns][0][r] + bvv0));
          v_out[(size_t)node * 64 + wv * 32 + 16 + c] =
              f32_to_bf16_rne(fast_tanh(acc[ns][1][r] + bvv1));
        }
      }
    }
  }
  __syncthreads();
  if (t < 64) {
    int node = node0b + t;
    if (node < n) s_out[node] = sP[0][t] + sP[1][t];
  }
}

// k_aggr v7 (reverted, proven 42.6us): 4 nodes per wave, group-pipelined.
// Lane = (node-slot q=l>>4, dim-group g=l&15). Next group's (rs,re,s) issue
// before current gathers; next group's (col, s[col]) right after current
// chunk-0 gathers. Accumulation order fixed -> bitwise deterministic.
__global__ __launch_bounds__(256) void k_aggr(const int* __restrict__ rs,
                                              const int* __restrict__ re,
                                              const int* __restrict__ col,
                                              const float* __restrict__ s,
                                              const float* __restrict__ be_p,
                                              const unsigned short* __restrict__ v,
                                              float* __restrict__ out, int n) {
  int wid = (int)((blockIdx.x * 256 + threadIdx.x) >> 6);
  int nwv = (int)gridDim.x * 4;
  int l = threadIdx.x & 63;
  int q = l >> 4;  // node slot 0..3
  int g = l & 15;  // dim group: dims g*4 .. g*4+3
  int qb = l & 48; // quarter base lane
  float be = be_p[0];
  int ngroups = (n + 3) >> 2;
  if (wid >= ngroups) return;

  // prefetch meta for first group
  int pnode = wid * 4 + q;
  bool pvn = pnode < n;
  int pe0 = pvn ? rs[pnode] : 0;
  int pe1 = pvn ? re[pnode] : 0;
  float psrow = pvn ? s[pnode] : 0.f;
  int pc;
  float psc;
  {
    int prem = pe1 - pe0;
    pc = (g < prem) ? col[pe0 + g] : 0;
    psc = (g < prem) ? s[pc] : 0.f;
  }

  for (int grp = wid; grp < ngroups; grp += nwv) {
    int e0 = pe0, e1 = pe1;
    float srow = psrow;
    int c0 = pc;
    float sc0 = psc;
    int nxt = grp + nwv;
    if (nxt < ngroups) {  // issue next group's meta loads now
      int nn = nxt * 4 + q;
      bool nv = nn < n;
      pe0 = nv ? rs[nn] : 0;
      pe1 = nv ? re[nn] : 0;
      psrow = nv ? s[nn] : 0.f;
    }
    int m = e1 - e0;  // this quarter's degree
    float a0 = 0.f, a1 = 0.f, a2 = 0.f, a3 = 0.f;
    float dl = 0.f;

    // chunk 0 (col + s[col] prefetched)
    {
      float w = (g < m) ? __expf(fast_tanh(srow + sc0 + be)) : 0.f;
      dl += w;
#pragma unroll
      for (int jj = 0; jj < 16; jj++) {
        int cj = __shfl(c0, qb + jj, 64);
        float wj = __shfl(w, qb + jj, 64);
        uint2 pk = *(const uint2*)(v + ((size_t)cj << 6) + (g << 2));
        a0 = fmaf(wj, __uint_as_float(pk.x << 16), a0);
        a1 = fmaf(wj, __uint_as_float(pk.x & 0xffff0000u), a1);
        a2 = fmaf(wj, __uint_as_float(pk.y << 16), a2);
        a3 = fmaf(wj, __uint_as_float(pk.y & 0xffff0000u), a3);
      }
    }
    // prefetch next group's chunk-0 col + s[col] (hides under epilogue)
    if (nxt < ngroups) {
      int nrem = pe1 - pe0;
      pc = (g < nrem) ? col[pe0 + g] : 0;
      psc = (g < nrem) ? s[pc] : 0.f;
    }
    // remaining chunks (degree > 16, ~43% of groups)
    for (int cb = 16; !__all(m - cb <= 0); cb += 16) {
      bool act = (cb + g) < m;
      int c = act ? col[e0 + cb + g] : 0;
      float w = act ? __expf(fast_tanh(srow + s[c] + be)) : 0.f;
      dl += w;
#pragma unroll
      for (int jj = 0; jj < 16; jj++) {
        int cj = __shfl(c, qb + jj, 64);
        float wj = __shfl(w, qb + jj, 64);
        uint2 pk = *(const uint2*)(v + ((size_t)cj << 6) + (g << 2));
        a0 = fmaf(wj, __uint_as_float(pk.x << 16), a0);
        a1 = fmaf(wj, __uint_as_float(pk.x & 0xffff0000u), a1);
        a2 = fmaf(wj, __uint_as_float(pk.y << 16), a2);
        a3 = fmaf(wj, __uint_as_float(pk.y & 0xffff0000u), a3);
      }
    }

    // epilogue: denom reduce (within quarter), stats, store
#pragma unroll
    for (int mm = 1; mm < 16; mm <<= 1) dl += __shfl_xor(dl, mm, 64);
    float inv = __builtin_amdgcn_rcpf(dl);
    float o0 = a0 * inv, o1 = a1 * inv, o2 = a2 * inv, o3 = a3 * inv;
    float t0 = o0 + o1 + o2 + o3;
    float t1 = o0 * o0 + o1 * o1 + o2 * o2 + o3 * o3;
#pragma unroll
    for (int mm = 1; mm < 16; mm <<= 1) {
      t0 += __shfl_xor(t0, mm, 64);
      t1 += __shfl_xor(t1, mm, 64);
    }
    float var = (t1 - t0 * t0 * (1.0f / 64.f)) * (1.0f / 63.f);
    float isd = __builtin_amdgcn_rsqf(var);
    int cnode = grp * 4 + q;
    if (cnode < n) {
      float4 r = {o0 * isd, o1 * isd, o2 * isd, o3 * isd};
      *(float4*)&out[(size_t)cnode * 64 + (g << 2)] = r;
    }
  }
}

extern "C" void kernel_launch(void* const* d_in, const int* in_sizes, int n_in,
                              void* d_out, int out_size, void* d_ws, size_t ws_size,
                              hipStream_t stream) {
  const float* h = (const float*)d_in[0];
  const int* ei = (const int*)d_in[1];
  const float* W11 = (const float*)d_in[2];
  const float* b11 = (const float*)d_in[3];
  const float* W12 = (const float*)d_in[4];  // [1,64] -> 64-vec
  const float* b12 = (const float*)d_in[5];
  const float* W13 = (const float*)d_in[6];
  const float* b13 = (const float*)d_in[7];
  const float* W21 = (const float*)d_in[8];
  const float* b21 = (const float*)d_in[9];
  const float* W22 = (const float*)d_in[10];
  const float* b22 = (const float*)d_in[11];
  const float* W23 = (const float*)d_in[12];
  const float* b23 = (const float*)d_in[13];

  const int N = in_sizes[0] / 128;  // 100000
  const int E = in_sizes[1] / 2;    // 1600000
  const int* src = ei;
  const int* dst = ei + E;
  const int NB = (N + BIN_NODES - 1) >> BIN_SHIFT;  // 782

  // workspace carve-up (~48 MB)
  char* p = (char*)d_ws;
  auto alloc = [&](size_t bytes) -> void* {
    void* r = (void*)p;
    p += (bytes + WS_ALIGN - 1) / WS_ALIGN * WS_ALIGN;
    return r;
  };
  int* cursor = (int*)alloc((size_t)NB * 4);
  int* binned = (int*)alloc((size_t)NB * BIN_CAP * 4);  // 8.0MB
  int* rsb = (int*)alloc((size_t)N * 4);
  int* reb = (int*)alloc((size_t)N * 4);
  float* sbuf = (float*)alloc((size_t)N * 4);
  unsigned short* vbuf = (unsigned short*)alloc((size_t)N * 64 * 2);  // bf16
  float* out1 = (float*)alloc((size_t)N * 64 * 4);
  short* Wh1 = (short*)alloc(128 * 128 * 2);
  short* Wl1 = (short*)alloc(128 * 128 * 2);
  short* Wh2 = (short*)alloc(128 * 64 * 2);
  short* Wl2 = (short*)alloc(128 * 64 * 2);

  // ---- setup: weight prep (both layers) + cursor init, one launch ----
  k_setup<<<(24576 + NB + 255) / 256, 256, 0, stream>>>(
      W11, W13, Wh1, Wl1, W21, W23, Wh2, Wl2, cursor, NB);

  // ---- CSR build via bin sort (reused by both layers) ----
  k_bin<<<(E + EPB - 1) / EPB, 256, 0, stream>>>(src, dst, cursor, binned, E, NB);
  k_sort_bin<<<NB, 256, 0, stream>>>(binned, cursor, rsb, reb, N);

  // ---- layer 1 (K=128) ----
  k_node<128><<<(N + 63) / 64, 256, 0, stream>>>(h, Wh1, Wl1, b11, W12, b13, vbuf, sbuf, N);
  k_aggr<<<AGGR_BLOCKS, 256, 0, stream>>>(rsb, reb, binned, sbuf, b12, vbuf, out1, N);

  // ---- layer 2 (K=64) ----
  k_node<64><<<(N + 63) / 64, 256, 0, stream>>>(out1, Wh2, Wl2, b21, W22, b23, vbuf, sbuf, N);
  k_aggr<<<AGGR_BLOCKS, 256, 0, stream>>>(rsb, reb, binned, sbuf, b22, vbuf, (float*)d_out, N);
}

// Round 12
// 277.371 us; speedup vs baseline: 1.0646x; 1.0154x over previous
//
#include <hip/hip_runtime.h>

// GAT 2-layer, N=100000 nodes, E=1.6M edges, dims 128->64->64, all fp32.
// Strategy:
//   - s[i] = a[i]·we collapses edge-logit GEMV to per-node scalar (We is [1,64]).
//   - tanh-bounded logits => skip segment_max (exp ratio identical).
//   - CSR build: coarse 128-node-bin counting sort + per-bin in-LDS sort.
//     R9: within-node DETERMINISTIC order (rank-sort by dst).
//   - k_node v2 (R13): register-stationary W frags, pre-converted bf16 hi/lo
//     LDS x-tile; inner loop = ds_read_b128 + MFMA only.
//   - k_aggr v7 @2048 blocks: proven floor 42.6us (R5). R6/R7/R8 burst/strip
//     variants all worse; R10 proved 1563 blocks worse (residency > balance).
//     ~205MB random 128B v-rows vs L3 (v > 4MB per-XCD L2) ~ the floor.
//   - R19/R20: FUSE independent kernels to overlap the serial pipeline
//     (no streams -> graph-safe):
//       memset(cursor) -> [k_bin || weight-prep] -> [k_node128 || k_sort_bin]
//       -> aggr1 -> k_node64 -> aggr2
//     cursor zero-based (memset-able); LDS unioned via char buffer in the
//     node||sort kernel. Determinism unchanged (rank-sort canonicalizes).
//     (R11 run lost to a stray-token compile error; fixed, resubmitted.)

#define WS_ALIGN 256
#define BIN_SHIFT 7
#define BIN_NODES 128
#define BIN_CAP 2560   // mean bin count 2048, sigma ~44 -> +11.6 sigma margin
#define MAX_BINS 1024
#define EPB 4096       // edges per k_bin block
#define AGGR_BLOCKS 2048

typedef __attribute__((ext_vector_type(8))) short short8;
typedef __attribute__((ext_vector_type(4))) short short4_t;
typedef __attribute__((ext_vector_type(4))) float f32x4;

__device__ __forceinline__ float fast_tanh(float x) {
  x = fminf(15.f, fmaxf(-15.f, x));
  float e = __expf(2.f * x);
  return (e - 1.f) * __builtin_amdgcn_rcpf(e + 1.f);
}

__device__ __forceinline__ unsigned short f32_to_bf16_rne(float f) {
  unsigned u = __float_as_uint(f);
  unsigned r = u + 0x7fffu + ((u >> 16) & 1u);
  return (unsigned short)(r >> 16);
}

// Split one element of [Wa;Wv] into bf16 hi/lo, FRAGMENT-LINEAR layout:
// i = (((nt*KBLK + kb)*4 + q)*16 + c)*8 + j  <->  W[nt*16+c][kb*32+q*8+j].
__device__ __forceinline__ void prepw_one(const float* __restrict__ Wa,
                                          const float* __restrict__ Wv,
                                          short* __restrict__ Wh, short* __restrict__ Wl,
                                          int K, int i) {
  int KBLK = K / 32;
  int j = i & 7;
  int c = (i >> 3) & 15;
  int q = (i >> 7) & 3;
  int r = i >> 9;  // nt*KBLK + kb
  int nt = r / KBLK, kb = r - nt * KBLK;
  int row = nt * 16 + c;
  int col = kb * 32 + q * 8 + j;
  float f = (row < 64) ? Wa[row * K + col] : Wv[(row - 64) * K + col];
  unsigned u = __float_as_uint(f);
  float hf = __uint_as_float(u & 0xffff0000u);
  Wh[i] = (short)(u >> 16);
  Wl[i] = (short)(__float_as_uint(f - hf) >> 16);
}

// Fused: blocks [0, binBlks) do edge binning; blocks [binBlks, ...) do weight
// prep for both layers. Independent work -> runs concurrently in one dispatch.
// cnt0 must be ZEROED before launch (hipMemsetAsync); positions are
// b*BIN_CAP + zero-based count.
__global__ __launch_bounds__(256) void k_bin_setup(
    const int* __restrict__ src, const int* __restrict__ dst,
    int* __restrict__ cnt0, int* __restrict__ binned, int E, int nb, int binBlks,
    const float* __restrict__ W11, const float* __restrict__ W13,
    short* __restrict__ Wh1, short* __restrict__ Wl1,
    const float* __restrict__ W21, const float* __restrict__ W23,
    short* __restrict__ Wh2, short* __restrict__ Wl2) {
  __shared__ int ssrc[EPB];
  __shared__ int sdst[EPB];
  __shared__ int hist[MAX_BINS];
  __shared__ int base[MAX_BINS];
  int t = threadIdx.x;
  if ((int)blockIdx.x >= binBlks) {
    // ---- weight-prep branch ----
    int i = ((int)blockIdx.x - binBlks) * 256 + t;
    if (i < 16384) {
      prepw_one(W11, W13, Wh1, Wl1, 128, i);
    } else if (i < 24576) {
      prepw_one(W21, W23, Wh2, Wl2, 64, i - 16384);
    }
    return;
  }
  // ---- binning branch ----
  for (int i = t; i < nb; i += 256) hist[i] = 0;
  __syncthreads();
  int e0 = (int)blockIdx.x * EPB;
  for (int i = t; i < EPB; i += 256) {
    int e = e0 + i;
    int sv = -1, dv = 0;
    if (e < E) {
      sv = src[e];
      dv = dst[e];
      atomicAdd(&hist[sv >> BIN_SHIFT], 1);
    }
    ssrc[i] = sv;
    sdst[i] = dv;
  }
  __syncthreads();
  for (int b = t; b < nb; b += 256) {
    int c = hist[b];
    base[b] = c ? (b * BIN_CAP + atomicAdd(&cnt0[b], c)) : 0;
    hist[b] = 0;
  }
  __syncthreads();
  for (int i = t; i < EPB; i += 256) {
    int sv = ssrc[i];
    if (sv >= 0) {
      int b = sv >> BIN_SHIFT;
      int r = atomicAdd(&hist[b], 1);
      int pos = base[b] + r;
      if (pos < (b + 1) * BIN_CAP)  // overflow guard (never expected to fire)
        binned[pos] = (sdst[i] << BIN_SHIFT) | (sv & (BIN_NODES - 1));
    }
  }
}

// ---- node-transform body (shared by fused and standalone kernels) ----
// D[node][0..127] = x[node][:] @ [Wa;Wv]^T, 16x16x32 bf16, hi/lo split.
// Block = 256 thr / 4 waves / 64 nodes; wave w owns n-tiles {2w,2w+1} with
// register-stationary W frags; x staged pre-converted in LDS (+8-short pad).
template <int K>
__device__ __forceinline__ void node_body(
    short* __restrict__ sah, short* __restrict__ sal, float* __restrict__ sP,
    int bid, const float* __restrict__ x, const short* __restrict__ Wh,
    const short* __restrict__ Wl, const float* __restrict__ ba,
    const float* __restrict__ we, const float* __restrict__ bv,
    unsigned short* __restrict__ v_out, float* __restrict__ s_out, int n) {
  constexpr int KBLK = K / 32;
  constexpr int RS = K + 8;  // shorts per LDS row (+16B pad)
  int t = threadIdx.x;
  int l = t & 63;
  int w = t >> 6;
  int q = l >> 4, c = l & 15;
  int node0b = bid * 64;

  // stage x tile: coalesced float4 read -> bf16 hi/lo split -> LDS
  {
    const float4* xg = (const float4*)(x + (size_t)node0b * K);
    constexpr int R4 = K / 4;
#pragma unroll
    for (int it = 0; it < 64 * R4 / 256; it++) {
      int i = it * 256 + t;
      int r = i / R4, k4 = i - r * R4;
      float4 val = (node0b + r < n) ? xg[i] : (float4){0.f, 0.f, 0.f, 0.f};
      float xv[4] = {val.x, val.y, val.z, val.w};
      short4_t hi, lo;
#pragma unroll
      for (int j = 0; j < 4; j++) {
        unsigned u = __float_as_uint(xv[j]);
        hi[j] = (short)(u >> 16);
        float hf = __uint_as_float(u & 0xffff0000u);
        lo[j] = (short)(__float_as_uint(xv[j] - hf) >> 16);
      }
      *(short4_t*)&sah[r * RS + k4 * 4] = hi;
      *(short4_t*)&sal[r * RS + k4 * 4] = lo;
    }
  }

  // one-time W fragment loads (register-stationary), overlap staging wait
  const short8* WhF = (const short8*)Wh;
  const short8* WlF = (const short8*)Wl;
  short8 wfh[2][KBLK], wfl[2][KBLK];
#pragma unroll
  for (int mt = 0; mt < 2; mt++)
#pragma unroll
    for (int kb = 0; kb < KBLK; kb++) {
      size_t f = (size_t)((2 * w + mt) * KBLK + kb) * 64 + l;
      wfh[mt][kb] = WhF[f];
      wfl[mt][kb] = WlF[f];
    }
  __syncthreads();

  f32x4 acc[4][2];
#pragma unroll
  for (int ns = 0; ns < 4; ns++)
#pragma unroll
    for (int mt = 0; mt < 2; mt++) acc[ns][mt] = (f32x4){0.f, 0.f, 0.f, 0.f};

#pragma unroll
  for (int ns = 0; ns < 4; ns++) {
#pragma unroll
    for (int kb = 0; kb < KBLK; kb++) {
      int off = (ns * 16 + c) * RS + kb * 32 + q * 8;
      short8 ah = *(const short8*)&sah[off];
      short8 al = *(const short8*)&sal[off];
#pragma unroll
      for (int mt = 0; mt < 2; mt++) {
        acc[ns][mt] = __builtin_amdgcn_mfma_f32_16x16x32_bf16(ah, wfh[mt][kb], acc[ns][mt], 0, 0, 0);
        acc[ns][mt] = __builtin_amdgcn_mfma_f32_16x16x32_bf16(ah, wfl[mt][kb], acc[ns][mt], 0, 0, 0);
        acc[ns][mt] = __builtin_amdgcn_mfma_f32_16x16x32_bf16(al, wfh[mt][kb], acc[ns][mt], 0, 0, 0);
      }
    }
  }

  // ---- epilogue ----
  if (w < 2) {
    float bav0 = ba[w * 32 + c], wev0 = we[w * 32 + c];
    float bav1 = ba[w * 32 + 16 + c], wev1 = we[w * 32 + 16 + c];
#pragma unroll
    for (int ns = 0; ns < 4; ns++) {
#pragma unroll
      for (int r = 0; r < 4; r++) {
        float pv = fast_tanh(acc[ns][0][r] + bav0) * wev0 +
                   fast_tanh(acc[ns][1][r] + bav1) * wev1;
#pragma unroll
        for (int mm = 1; mm < 16; mm <<= 1) pv += __shfl_xor(pv, mm, 64);
        if (c == 0) sP[w * 64 + ns * 16 + q * 4 + r] = pv;
      }
    }
  } else {
    int wv = w - 2;
    float bvv0 = bv[wv * 32 + c], bvv1 = bv[wv * 32 + 16 + c];
#pragma unroll
    for (int ns = 0; ns < 4; ns++) {
#pragma unroll
      for (int r = 0; r < 4; r++) {
        int node = node0b + ns * 16 + q * 4 + r;
        if (node < n) {
          v_out[(size_t)node * 64 + wv * 32 + c] =
              f32_to_bf16_rne(fast_tanh(acc[ns][0][r] + bvv0));
          v_out[(size_t)node * 64 + wv * 32 + 16 + c] =
              f32_to_bf16_rne(fast_tanh(acc[ns][1][r] + bvv1));
        }
      }
    }
  }
  __syncthreads();
  if (t < 64) {
    int node = node0b + t;
    if (node < n) s_out[node] = sP[t] + sP[64 + t];
  }
}

// ---- per-bin sort body (counting sort + deterministic rank-sort) ----
__device__ __forceinline__ void sort_body(
    int* __restrict__ ents, int* __restrict__ sorted, int* __restrict__ hist,
    int* __restrict__ scan, int* __restrict__ cur, int bin,
    int* __restrict__ binned, const int* __restrict__ cnt0,
    int* __restrict__ rs, int* __restrict__ re, int n) {
  int t = threadIdx.x;
  int nbase = bin << BIN_SHIFT;
  int cnt = cnt0[bin];
  if (cnt > BIN_CAP) cnt = BIN_CAP;
  if (t < BIN_NODES) hist[t] = 0;
  __syncthreads();
  int* bp = binned + (size_t)bin * BIN_CAP;
  for (int i = t; i < cnt; i += 256) {
    int pk = bp[i];
    ents[i] = pk;
    atomicAdd(&hist[pk & (BIN_NODES - 1)], 1);
  }
  __syncthreads();
  if (t < BIN_NODES) scan[t] = hist[t];
  __syncthreads();
  for (int off = 1; off < BIN_NODES; off <<= 1) {
    int add = (t < BIN_NODES && t >= off) ? scan[t - off] : 0;
    __syncthreads();
    if (t < BIN_NODES) scan[t] += add;
    __syncthreads();
  }
  if (t < BIN_NODES) {
    int ex = scan[t] - hist[t];  // exclusive
    cur[t] = ex;
    int node = nbase + t;
    if (node < n) {
      rs[node] = bin * BIN_CAP + ex;
      re[node] = bin * BIN_CAP + ex + hist[t];
    }
  }
  __syncthreads();
  // scatter by node (keep full pk — needed for the rank pass)
  for (int i = t; i < cnt; i += 256) {
    int pk = ents[i];
    int pos = atomicAdd(&cur[pk & (BIN_NODES - 1)], 1);
    sorted[pos] = pk;
  }
  __syncthreads();
  // deterministic rank-sort within each node segment, ascending by dst.
  for (int i = t; i < cnt; i += 256) {
    int pk = sorted[i];
    int node = pk & (BIN_NODES - 1);
    int hi = scan[node];
    int lo = hi - hist[node];
    int r = lo;
    for (int j = lo; j < hi; j++) {
      int pj = sorted[j];
      r += (pj < pk) || (pj == pk && j < i);
    }
    ents[r] = pk >> BIN_SHIFT;  // keep dst only
  }
  __syncthreads();
  for (int i = t; i < cnt; i += 256) bp[i] = ents[i];  // coalesced write-back
}

// Fused: blocks [0, nodeBlks) run k_node<128>; blocks [nodeBlks, ...) run the
// per-bin sort. Independent work (node needs weights, sort needs binned) ->
// concurrent in one dispatch; LDS unioned in a char buffer.
__global__ __launch_bounds__(256) void k_node128_sort(
    int nodeBlks,
    const float* __restrict__ x, const short* __restrict__ Wh,
    const short* __restrict__ Wl, const float* __restrict__ ba,
    const float* __restrict__ we, const float* __restrict__ bv,
    unsigned short* __restrict__ v_out, float* __restrict__ s_out, int n,
    int* __restrict__ binned, const int* __restrict__ cnt0,
    int* __restrict__ rs, int* __restrict__ re) {
  // node<128>: 2*64*136 shorts + 128 floats = 35328B ; sort: 22016B
  __shared__ __align__(16) char smem[64 * 136 * 4 + 512];
  if ((int)blockIdx.x < nodeBlks) {
    short* sah = (short*)smem;
    short* sal = (short*)(smem + 64 * 136 * 2);
    float* sP = (float*)(smem + 64 * 136 * 4);
    node_body<128>(sah, sal, sP, (int)blockIdx.x, x, Wh, Wl, ba, we, bv,
                   v_out, s_out, n);
  } else {
    int* ents = (int*)smem;
    int* sorted = ents + BIN_CAP;
    int* hist = sorted + BIN_CAP;
    int* scan = hist + BIN_NODES;
    int* cur = scan + BIN_NODES;
    sort_body(ents, sorted, hist, scan, cur, (int)blockIdx.x - nodeBlks,
              binned, cnt0, rs, re, n);
  }
}

// Standalone node kernel for layer 2 (K=64).
template <int K>
__global__ __launch_bounds__(256) void k_node(
    const float* __restrict__ x, const short* __restrict__ Wh,
    const short* __restrict__ Wl, const float* __restrict__ ba,
    const float* __restrict__ we, const float* __restrict__ bv,
    unsigned short* __restrict__ v_out, float* __restrict__ s_out, int n) {
  __shared__ short sah[64 * (K + 8)];
  __shared__ short sal[64 * (K + 8)];
  __shared__ float sP[2 * 64];
  node_body<K>(sah, sal, sP, (int)blockIdx.x, x, Wh, Wl, ba, we, bv,
               v_out, s_out, n);
}

// k_aggr v7 (proven 42.6us @2048 blocks): 4 nodes per wave, group-pipelined.
// Lane = (node-slot q=l>>4, dim-group g=l&15). Next group's (rs,re,s) issue
// before current gathers; next group's (col, s[col]) right after current
// chunk-0 gathers. Accumulation order fixed -> bitwise deterministic.
__global__ __launch_bounds__(256) void k_aggr(const int* __restrict__ rs,
                                              const int* __restrict__ re,
                                              const int* __restrict__ col,
                                              const float* __restrict__ s,
                                              const float* __restrict__ be_p,
                                              const unsigned short* __restrict__ v,
                                              float* __restrict__ out, int n) {
  int wid = (int)((blockIdx.x * 256 + threadIdx.x) >> 6);
  int nwv = (int)gridDim.x * 4;
  int l = threadIdx.x & 63;
  int q = l >> 4;  // node slot 0..3
  int g = l & 15;  // dim group: dims g*4 .. g*4+3
  int qb = l & 48; // quarter base lane
  float be = be_p[0];
  int ngroups = (n + 3) >> 2;
  if (wid >= ngroups) return;

  // prefetch meta for first group
  int pnode = wid * 4 + q;
  bool pvn = pnode < n;
  int pe0 = pvn ? rs[pnode] : 0;
  int pe1 = pvn ? re[pnode] : 0;
  float psrow = pvn ? s[pnode] : 0.f;
  int pc;
  float psc;
  {
    int prem = pe1 - pe0;
    pc = (g < prem) ? col[pe0 + g] : 0;
    psc = (g < prem) ? s[pc] : 0.f;
  }

  for (int grp = wid; grp < ngroups; grp += nwv) {
    int e0 = pe0, e1 = pe1;
    float srow = psrow;
    int c0 = pc;
    float sc0 = psc;
    int nxt = grp + nwv;
    if (nxt < ngroups) {  // issue next group's meta loads now
      int nn = nxt * 4 + q;
      bool nv = nn < n;
      pe0 = nv ? rs[nn] : 0;
      pe1 = nv ? re[nn] : 0;
      psrow = nv ? s[nn] : 0.f;
    }
    int m = e1 - e0;  // this quarter's degree
    float a0 = 0.f, a1 = 0.f, a2 = 0.f, a3 = 0.f;
    float dl = 0.f;

    // chunk 0 (col + s[col] prefetched)
    {
      float w = (g < m) ? __expf(fast_tanh(srow + sc0 + be)) : 0.f;
      dl += w;
#pragma unroll
      for (int jj = 0; jj < 16; jj++) {
        int cj = __shfl(c0, qb + jj, 64);
        float wj = __shfl(w, qb + jj, 64);
        uint2 pk = *(const uint2*)(v + ((size_t)cj << 6) + (g << 2));
        a0 = fmaf(wj, __uint_as_float(pk.x << 16), a0);
        a1 = fmaf(wj, __uint_as_float(pk.x & 0xffff0000u), a1);
        a2 = fmaf(wj, __uint_as_float(pk.y << 16), a2);
        a3 = fmaf(wj, __uint_as_float(pk.y & 0xffff0000u), a3);
      }
    }
    // prefetch next group's chunk-0 col + s[col] (hides under epilogue)
    if (nxt < ngroups) {
      int nrem = pe1 - pe0;
      pc = (g < nrem) ? col[pe0 + g] : 0;
      psc = (g < nrem) ? s[pc] : 0.f;
    }
    // remaining chunks (degree > 16, ~43% of groups)
    for (int cb = 16; !__all(m - cb <= 0); cb += 16) {
      bool act = (cb + g) < m;
      int c = act ? col[e0 + cb + g] : 0;
      float w = act ? __expf(fast_tanh(srow + s[c] + be)) : 0.f;
      dl += w;
#pragma unroll
      for (int jj = 0; jj < 16; jj++) {
        int cj = __shfl(c, qb + jj, 64);
        float wj = __shfl(w, qb + jj, 64);
        uint2 pk = *(const uint2*)(v + ((size_t)cj << 6) + (g << 2));
        a0 = fmaf(wj, __uint_as_float(pk.x << 16), a0);
        a1 = fmaf(wj, __uint_as_float(pk.x & 0xffff0000u), a1);
        a2 = fmaf(wj, __uint_as_float(pk.y << 16), a2);
        a3 = fmaf(wj, __uint_as_float(pk.y & 0xffff0000u), a3);
      }
    }

    // epilogue: denom reduce (within quarter), stats, store
#pragma unroll
    for (int mm = 1; mm < 16; mm <<= 1) dl += __shfl_xor(dl, mm, 64);
    float inv = __builtin_amdgcn_rcpf(dl);
    float o0 = a0 * inv, o1 = a1 * inv, o2 = a2 * inv, o3 = a3 * inv;
    float t0 = o0 + o1 + o2 + o3;
    float t1 = o0 * o0 + o1 * o1 + o2 * o2 + o3 * o3;
#pragma unroll
    for (int mm = 1; mm < 16; mm <<= 1) {
      t0 += __shfl_xor(t0, mm, 64);
      t1 += __shfl_xor(t1, mm, 64);
    }
    float var = (t1 - t0 * t0 * (1.0f / 64.f)) * (1.0f / 63.f);
    float isd = __builtin_amdgcn_rsqf(var);
    int cnode = grp * 4 + q;
    if (cnode < n) {
      float4 r = {o0 * isd, o1 * isd, o2 * isd, o3 * isd};
      *(float4*)&out[(size_t)cnode * 64 + (g << 2)] = r;
    }
  }
}

extern "C" void kernel_launch(void* const* d_in, const int* in_sizes, int n_in,
                              void* d_out, int out_size, void* d_ws, size_t ws_size,
                              hipStream_t stream) {
  const float* h = (const float*)d_in[0];
  const int* ei = (const int*)d_in[1];
  const float* W11 = (const float*)d_in[2];
  const float* b11 = (const float*)d_in[3];
  const float* W12 = (const float*)d_in[4];  // [1,64] -> 64-vec
  const float* b12 = (const float*)d_in[5];
  const float* W13 = (const float*)d_in[6];
  const float* b13 = (const float*)d_in[7];
  const float* W21 = (const float*)d_in[8];
  const float* b21 = (const float*)d_in[9];
  const float* W22 = (const float*)d_in[10];
  const float* b22 = (const float*)d_in[11];
  const float* W23 = (const float*)d_in[12];
  const float* b23 = (const float*)d_in[13];

  const int N = in_sizes[0] / 128;  // 100000
  const int E = in_sizes[1] / 2;    // 1600000
  const int* src = ei;
  const int* dst = ei + E;
  const int NB = (N + BIN_NODES - 1) >> BIN_SHIFT;  // 782

  // workspace carve-up (~48 MB)
  char* p = (char*)d_ws;
  auto alloc = [&](size_t bytes) -> void* {
    void* r = (void*)p;
    p += (bytes + WS_ALIGN - 1) / WS_ALIGN * WS_ALIGN;
    return r;
  };
  int* cursor = (int*)alloc((size_t)NB * 4);
  int* binned = (int*)alloc((size_t)NB * BIN_CAP * 4);  // 8.0MB
  int* rsb = (int*)alloc((size_t)N * 4);
  int* reb = (int*)alloc((size_t)N * 4);
  float* sbuf = (float*)alloc((size_t)N * 4);
  unsigned short* vbuf = (unsigned short*)alloc((size_t)N * 64 * 2);  // bf16
  float* out1 = (float*)alloc((size_t)N * 64 * 4);
  short* Wh1 = (short*)alloc(128 * 128 * 2);
  short* Wl1 = (short*)alloc(128 * 128 * 2);
  short* Wh2 = (short*)alloc(128 * 64 * 2);
  short* Wl2 = (short*)alloc(128 * 64 * 2);

  const int BIN_BLKS = (E + EPB - 1) / EPB;  // 391
  const int SETUP_BLKS = 24576 / 256;        // 96
  const int NODE_BLKS = (N + 63) / 64;       // 1563

  // ---- zero cursor (graph-capturable), then fused bin || weight-prep ----
  (void)hipMemsetAsync(cursor, 0, (size_t)NB * 4, stream);
  k_bin_setup<<<BIN_BLKS + SETUP_BLKS, 256, 0, stream>>>(
      src, dst, cursor, binned, E, NB, BIN_BLKS,
      W11, W13, Wh1, Wl1, W21, W23, Wh2, Wl2);

  // ---- fused k_node<128> || per-bin sort (independent) ----
  k_node128_sort<<<NODE_BLKS + NB, 256, 0, stream>>>(
      NODE_BLKS, h, Wh1, Wl1, b11, W12, b13, vbuf, sbuf, N,
      binned, cursor, rsb, reb);

  // ---- layer 1 aggregation ----
  k_aggr<<<AGGR_BLOCKS, 256, 0, stream>>>(rsb, reb, binned, sbuf, b12, vbuf, out1, N);

  // ---- layer 2 (K=64) ----
  k_node<64><<<NODE_BLKS, 256, 0, stream>>>(out1, Wh2, Wl2, b21, W22, b23, vbuf, sbuf, N);
  k_aggr<<<AGGR_BLOCKS, 256, 0, stream>>>(rsb, reb, binned, sbuf, b22, vbuf, (float*)d_out, N);
}

// Round 14
// 270.900 us; speedup vs baseline: 1.0901x; 1.0239x over previous
//
#include <hip/hip_runtime.h>

// GAT 2-layer, N=100000 nodes, E=1.6M edges, dims 128->64->64, all fp32.
// Strategy:
//   - s[i] = a[i]·we collapses edge-logit GEMV to per-node scalar (We is [1,64]).
//   - tanh-bounded logits => skip segment_max (exp ratio identical).
//   - CSR build: coarse 128-node-bin counting sort + per-bin in-LDS sort.
//     R9: within-node DETERMINISTIC order (rank-sort by dst).
//   - k_aggr v7 @2048 blocks: proven floor 42.6us (R5-R10: 5 redesigns lost).
//   - R19/R20 fusion: memset(cursor) -> [k_bin || weight-prep] ->
//     [k_node128 || k_sort_bin] -> aggr1 -> k_node64 -> aggr2. 277.4us.
//   - R21/R22: R12 counters show fused node kernel at 1.0TB/s HBM,
//     MfmaUtil 7.4%, occ 31% -> STAGING-CONCURRENCY bound (35KB LDS = 4
//     blocks/CU). Node tile 64 -> 32 nodes (node_body<K,ROWS=32>): LDS 17.7KB
//     under the 22KB sort union -> 7 blocks/CU, 2x blocks (3125) -> ~2x
//     concurrent HBM refills. Same per-node arithmetic/order -> bitwise
//     deterministic. W reload doubles but W is 64KB L2-resident.
//     (R13 run lost to container failure; resubmitted unchanged.)

#define WS_ALIGN 256
#define BIN_SHIFT 7
#define BIN_NODES 128
#define BIN_CAP 2560   // mean bin count 2048, sigma ~44 -> +11.6 sigma margin
#define MAX_BINS 1024
#define EPB 4096       // edges per k_bin block
#define AGGR_BLOCKS 2048
#define NROWS 32       // nodes per node-transform block (R21)

typedef __attribute__((ext_vector_type(8))) short short8;
typedef __attribute__((ext_vector_type(4))) short short4_t;
typedef __attribute__((ext_vector_type(4))) float f32x4;

__device__ __forceinline__ float fast_tanh(float x) {
  x = fminf(15.f, fmaxf(-15.f, x));
  float e = __expf(2.f * x);
  return (e - 1.f) * __builtin_amdgcn_rcpf(e + 1.f);
}

__device__ __forceinline__ unsigned short f32_to_bf16_rne(float f) {
  unsigned u = __float_as_uint(f);
  unsigned r = u + 0x7fffu + ((u >> 16) & 1u);
  return (unsigned short)(r >> 16);
}

// Split one element of [Wa;Wv] into bf16 hi/lo, FRAGMENT-LINEAR layout:
// i = (((nt*KBLK + kb)*4 + q)*16 + c)*8 + j  <->  W[nt*16+c][kb*32+q*8+j].
__device__ __forceinline__ void prepw_one(const float* __restrict__ Wa,
                                          const float* __restrict__ Wv,
                                          short* __restrict__ Wh, short* __restrict__ Wl,
                                          int K, int i) {
  int KBLK = K / 32;
  int j = i & 7;
  int c = (i >> 3) & 15;
  int q = (i >> 7) & 3;
  int r = i >> 9;  // nt*KBLK + kb
  int nt = r / KBLK, kb = r - nt * KBLK;
  int row = nt * 16 + c;
  int col = kb * 32 + q * 8 + j;
  float f = (row < 64) ? Wa[row * K + col] : Wv[(row - 64) * K + col];
  unsigned u = __float_as_uint(f);
  float hf = __uint_as_float(u & 0xffff0000u);
  Wh[i] = (short)(u >> 16);
  Wl[i] = (short)(__float_as_uint(f - hf) >> 16);
}

// Fused: blocks [0, binBlks) do edge binning; blocks [binBlks, ...) do weight
// prep for both layers. Independent work -> concurrent in one dispatch.
// cnt0 must be ZEROED before launch (hipMemsetAsync).
__global__ __launch_bounds__(256) void k_bin_setup(
    const int* __restrict__ src, const int* __restrict__ dst,
    int* __restrict__ cnt0, int* __restrict__ binned, int E, int nb, int binBlks,
    const float* __restrict__ W11, const float* __restrict__ W13,
    short* __restrict__ Wh1, short* __restrict__ Wl1,
    const float* __restrict__ W21, const float* __restrict__ W23,
    short* __restrict__ Wh2, short* __restrict__ Wl2) {
  __shared__ int ssrc[EPB];
  __shared__ int sdst[EPB];
  __shared__ int hist[MAX_BINS];
  __shared__ int base[MAX_BINS];
  int t = threadIdx.x;
  if ((int)blockIdx.x >= binBlks) {
    // ---- weight-prep branch ----
    int i = ((int)blockIdx.x - binBlks) * 256 + t;
    if (i < 16384) {
      prepw_one(W11, W13, Wh1, Wl1, 128, i);
    } else if (i < 24576) {
      prepw_one(W21, W23, Wh2, Wl2, 64, i - 16384);
    }
    return;
  }
  // ---- binning branch ----
  for (int i = t; i < nb; i += 256) hist[i] = 0;
  __syncthreads();
  int e0 = (int)blockIdx.x * EPB;
  for (int i = t; i < EPB; i += 256) {
    int e = e0 + i;
    int sv = -1, dv = 0;
    if (e < E) {
      sv = src[e];
      dv = dst[e];
      atomicAdd(&hist[sv >> BIN_SHIFT], 1);
    }
    ssrc[i] = sv;
    sdst[i] = dv;
  }
  __syncthreads();
  for (int b = t; b < nb; b += 256) {
    int c = hist[b];
    base[b] = c ? (b * BIN_CAP + atomicAdd(&cnt0[b], c)) : 0;
    hist[b] = 0;
  }
  __syncthreads();
  for (int i = t; i < EPB; i += 256) {
    int sv = ssrc[i];
    if (sv >= 0) {
      int b = sv >> BIN_SHIFT;
      int r = atomicAdd(&hist[b], 1);
      int pos = base[b] + r;
      if (pos < (b + 1) * BIN_CAP)  // overflow guard (never expected to fire)
        binned[pos] = (sdst[i] << BIN_SHIFT) | (sv & (BIN_NODES - 1));
    }
  }
}

// ---- node-transform body ----
// D[node][0..127] = x[node][:] @ [Wa;Wv]^T, 16x16x32 bf16, hi/lo split.
// Block = 256 thr / 4 waves / ROWS nodes; wave w owns output n-tiles
// {2w,2w+1} (register-stationary W frags), iterates ROWS/16 node-subtiles
// from a pre-converted bf16 hi/lo LDS x-tile (+8-short pad -> free 2-way).
// Waves 0,1 produce a-dim partial s (combined via sP); waves 2,3 write v.
template <int K, int ROWS>
__device__ __forceinline__ void node_body(
    short* __restrict__ sah, short* __restrict__ sal, float* __restrict__ sP,
    int bid, const float* __restrict__ x, const short* __restrict__ Wh,
    const short* __restrict__ Wl, const float* __restrict__ ba,
    const float* __restrict__ we, const float* __restrict__ bv,
    unsigned short* __restrict__ v_out, float* __restrict__ s_out, int n) {
  constexpr int KBLK = K / 32;
  constexpr int RS = K + 8;  // shorts per LDS row (+16B pad)
  constexpr int NS = ROWS / 16;
  int t = threadIdx.x;
  int l = t & 63;
  int w = t >> 6;
  int q = l >> 4, c = l & 15;
  int node0b = bid * ROWS;

  // stage x tile: coalesced float4 read -> bf16 hi/lo split -> LDS
  {
    const float4* xg = (const float4*)(x + (size_t)node0b * K);
    constexpr int R4 = K / 4;
#pragma unroll
    for (int it = 0; it < ROWS * R4 / 256; it++) {
      int i = it * 256 + t;
      int r = i / R4, k4 = i - r * R4;
      float4 val = (node0b + r < n) ? xg[i] : (float4){0.f, 0.f, 0.f, 0.f};
      float xv[4] = {val.x, val.y, val.z, val.w};
      short4_t hi, lo;
#pragma unroll
      for (int j = 0; j < 4; j++) {
        unsigned u = __float_as_uint(xv[j]);
        hi[j] = (short)(u >> 16);
        float hf = __uint_as_float(u & 0xffff0000u);
        lo[j] = (short)(__float_as_uint(xv[j] - hf) >> 16);
      }
      *(short4_t*)&sah[r * RS + k4 * 4] = hi;
      *(short4_t*)&sal[r * RS + k4 * 4] = lo;
    }
  }

  // one-time W fragment loads (register-stationary), overlap staging wait
  const short8* WhF = (const short8*)Wh;
  const short8* WlF = (const short8*)Wl;
  short8 wfh[2][KBLK], wfl[2][KBLK];
#pragma unroll
  for (int mt = 0; mt < 2; mt++)
#pragma unroll
    for (int kb = 0; kb < KBLK; kb++) {
      size_t f = (size_t)((2 * w + mt) * KBLK + kb) * 64 + l;
      wfh[mt][kb] = WhF[f];
      wfl[mt][kb] = WlF[f];
    }
  __syncthreads();

  f32x4 acc[NS][2];
#pragma unroll
  for (int ns = 0; ns < NS; ns++)
#pragma unroll
    for (int mt = 0; mt < 2; mt++) acc[ns][mt] = (f32x4){0.f, 0.f, 0.f, 0.f};

#pragma unroll
  for (int ns = 0; ns < NS; ns++) {
#pragma unroll
    for (int kb = 0; kb < KBLK; kb++) {
      int off = (ns * 16 + c) * RS + kb * 32 + q * 8;
      short8 ah = *(const short8*)&sah[off];
      short8 al = *(const short8*)&sal[off];
#pragma unroll
      for (int mt = 0; mt < 2; mt++) {
        acc[ns][mt] = __builtin_amdgcn_mfma_f32_16x16x32_bf16(ah, wfh[mt][kb], acc[ns][mt], 0, 0, 0);
        acc[ns][mt] = __builtin_amdgcn_mfma_f32_16x16x32_bf16(ah, wfl[mt][kb], acc[ns][mt], 0, 0, 0);
        acc[ns][mt] = __builtin_amdgcn_mfma_f32_16x16x32_bf16(al, wfh[mt][kb], acc[ns][mt], 0, 0, 0);
      }
    }
  }

  // ---- epilogue ----
  if (w < 2) {
    float bav0 = ba[w * 32 + c], wev0 = we[w * 32 + c];
    float bav1 = ba[w * 32 + 16 + c], wev1 = we[w * 32 + 16 + c];
#pragma unroll
    for (int ns = 0; ns < NS; ns++) {
#pragma unroll
      for (int r = 0; r < 4; r++) {
        float pv = fast_tanh(acc[ns][0][r] + bav0) * wev0 +
                   fast_tanh(acc[ns][1][r] + bav1) * wev1;
#pragma unroll
        for (int mm = 1; mm < 16; mm <<= 1) pv += __shfl_xor(pv, mm, 64);
        if (c == 0) sP[w * ROWS + ns * 16 + q * 4 + r] = pv;
      }
    }
  } else {
    int wv = w - 2;
    float bvv0 = bv[wv * 32 + c], bvv1 = bv[wv * 32 + 16 + c];
#pragma unroll
    for (int ns = 0; ns < NS; ns++) {
#pragma unroll
      for (int r = 0; r < 4; r++) {
        int node = node0b + ns * 16 + q * 4 + r;
        if (node < n) {
          v_out[(size_t)node * 64 + wv * 32 + c] =
              f32_to_bf16_rne(fast_tanh(acc[ns][0][r] + bvv0));
          v_out[(size_t)node * 64 + wv * 32 + 16 + c] =
              f32_to_bf16_rne(fast_tanh(acc[ns][1][r] + bvv1));
        }
      }
    }
  }
  __syncthreads();
  if (t < ROWS) {
    int node = node0b + t;
    if (node < n) s_out[node] = sP[t] + sP[ROWS + t];
  }
}

// ---- per-bin sort body (counting sort + deterministic rank-sort) ----
__device__ __forceinline__ void sort_body(
    int* __restrict__ ents, int* __restrict__ sorted, int* __restrict__ hist,
    int* __restrict__ scan, int* __restrict__ cur, int bin,
    int* __restrict__ binned, const int* __restrict__ cnt0,
    int* __restrict__ rs, int* __restrict__ re, int n) {
  int t = threadIdx.x;
  int nbase = bin << BIN_SHIFT;
  int cnt = cnt0[bin];
  if (cnt > BIN_CAP) cnt = BIN_CAP;
  if (t < BIN_NODES) hist[t] = 0;
  __syncthreads();
  int* bp = binned + (size_t)bin * BIN_CAP;
  for (int i = t; i < cnt; i += 256) {
    int pk = bp[i];
    ents[i] = pk;
    atomicAdd(&hist[pk & (BIN_NODES - 1)], 1);
  }
  __syncthreads();
  if (t < BIN_NODES) scan[t] = hist[t];
  __syncthreads();
  for (int off = 1; off < BIN_NODES; off <<= 1) {
    int add = (t < BIN_NODES && t >= off) ? scan[t - off] : 0;
    __syncthreads();
    if (t < BIN_NODES) scan[t] += add;
    __syncthreads();
  }
  if (t < BIN_NODES) {
    int ex = scan[t] - hist[t];  // exclusive
    cur[t] = ex;
    int node = nbase + t;
    if (node < n) {
      rs[node] = bin * BIN_CAP + ex;
      re[node] = bin * BIN_CAP + ex + hist[t];
    }
  }
  __syncthreads();
  // scatter by node (keep full pk — needed for the rank pass)
  for (int i = t; i < cnt; i += 256) {
    int pk = ents[i];
    int pos = atomicAdd(&cur[pk & (BIN_NODES - 1)], 1);
    sorted[pos] = pk;
  }
  __syncthreads();
  // deterministic rank-sort within each node segment, ascending by dst.
  for (int i = t; i < cnt; i += 256) {
    int pk = sorted[i];
    int node = pk & (BIN_NODES - 1);
    int hi = scan[node];
    int lo = hi - hist[node];
    int r = lo;
    for (int j = lo; j < hi; j++) {
      int pj = sorted[j];
      r += (pj < pk) || (pj == pk && j < i);
    }
    ents[r] = pk >> BIN_SHIFT;  // keep dst only
  }
  __syncthreads();
  for (int i = t; i < cnt; i += 256) bp[i] = ents[i];  // coalesced write-back
}

// Fused: blocks [0, nodeBlks) run node<128,32>; blocks [nodeBlks, ...) run
// the per-bin sort. Independent work -> concurrent; LDS unioned (22.3KB ->
// 7 blocks/CU).
__global__ __launch_bounds__(256) void k_node128_sort(
    int nodeBlks,
    const float* __restrict__ x, const short* __restrict__ Wh,
    const short* __restrict__ Wl, const float* __restrict__ ba,
    const float* __restrict__ we, const float* __restrict__ bv,
    unsigned short* __restrict__ v_out, float* __restrict__ s_out, int n,
    int* __restrict__ binned, const int* __restrict__ cnt0,
    int* __restrict__ rs, int* __restrict__ re) {
  // node<128,32>: 2*32*136 shorts + 64 floats = 17664B ; sort: 22016B
  __shared__ __align__(16) char smem[22272];
  if ((int)blockIdx.x < nodeBlks) {
    short* sah = (short*)smem;
    short* sal = (short*)(smem + NROWS * 136 * 2);
    float* sP = (float*)(smem + NROWS * 136 * 4);
    node_body<128, NROWS>(sah, sal, sP, (int)blockIdx.x, x, Wh, Wl, ba, we, bv,
                          v_out, s_out, n);
  } else {
    int* ents = (int*)smem;
    int* sorted = ents + BIN_CAP;
    int* hist = sorted + BIN_CAP;
    int* scan = hist + BIN_NODES;
    int* cur = scan + BIN_NODES;
    sort_body(ents, sorted, hist, scan, cur, (int)blockIdx.x - nodeBlks,
              binned, cnt0, rs, re, n);
  }
}

// Standalone node kernel for layer 2 (K=64, 32-node blocks, 9.5KB LDS).
template <int K>
__global__ __launch_bounds__(256) void k_node(
    const float* __restrict__ x, const short* __restrict__ Wh,
    const short* __restrict__ Wl, const float* __restrict__ ba,
    const float* __restrict__ we, const float* __restrict__ bv,
    unsigned short* __restrict__ v_out, float* __restrict__ s_out, int n) {
  __shared__ short sah[NROWS * (K + 8)];
  __shared__ short sal[NROWS * (K + 8)];
  __shared__ float sP[2 * NROWS];
  node_body<K, NROWS>(sah, sal, sP, (int)blockIdx.x, x, Wh, Wl, ba, we, bv,
                      v_out, s_out, n);
}

// k_aggr v7 (proven 42.6us @2048 blocks): 4 nodes per wave, group-pipelined.
// Lane = (node-slot q=l>>4, dim-group g=l&15). Next group's (rs,re,s) issue
// before current gathers; next group's (col, s[col]) right after current
// chunk-0 gathers. Accumulation order fixed -> bitwise deterministic.
__global__ __launch_bounds__(256) void k_aggr(const int* __restrict__ rs,
                                              const int* __restrict__ re,
                                              const int* __restrict__ col,
                                              const float* __restrict__ s,
                                              const float* __restrict__ be_p,
                                              const unsigned short* __restrict__ v,
                                              float* __restrict__ out, int n) {
  int wid = (int)((blockIdx.x * 256 + threadIdx.x) >> 6);
  int nwv = (int)gridDim.x * 4;
  int l = threadIdx.x & 63;
  int q = l >> 4;  // node slot 0..3
  int g = l & 15;  // dim group: dims g*4 .. g*4+3
  int qb = l & 48; // quarter base lane
  float be = be_p[0];
  int ngroups = (n + 3) >> 2;
  if (wid >= ngroups) return;

  // prefetch meta for first group
  int pnode = wid * 4 + q;
  bool pvn = pnode < n;
  int pe0 = pvn ? rs[pnode] : 0;
  int pe1 = pvn ? re[pnode] : 0;
  float psrow = pvn ? s[pnode] : 0.f;
  int pc;
  float psc;
  {
    int prem = pe1 - pe0;
    pc = (g < prem) ? col[pe0 + g] : 0;
    psc = (g < prem) ? s[pc] : 0.f;
  }

  for (int grp = wid; grp < ngroups; grp += nwv) {
    int e0 = pe0, e1 = pe1;
    float srow = psrow;
    int c0 = pc;
    float sc0 = psc;
    int nxt = grp + nwv;
    if (nxt < ngroups) {  // issue next group's meta loads now
      int nn = nxt * 4 + q;
      bool nv = nn < n;
      pe0 = nv ? rs[nn] : 0;
      pe1 = nv ? re[nn] : 0;
      psrow = nv ? s[nn] : 0.f;
    }
    int m = e1 - e0;  // this quarter's degree
    float a0 = 0.f, a1 = 0.f, a2 = 0.f, a3 = 0.f;
    float dl = 0.f;

    // chunk 0 (col + s[col] prefetched)
    {
      float w = (g < m) ? __expf(fast_tanh(srow + sc0 + be)) : 0.f;
      dl += w;
#pragma unroll
      for (int jj = 0; jj < 16; jj++) {
        int cj = __shfl(c0, qb + jj, 64);
        float wj = __shfl(w, qb + jj, 64);
        uint2 pk = *(const uint2*)(v + ((size_t)cj << 6) + (g << 2));
        a0 = fmaf(wj, __uint_as_float(pk.x << 16), a0);
        a1 = fmaf(wj, __uint_as_float(pk.x & 0xffff0000u), a1);
        a2 = fmaf(wj, __uint_as_float(pk.y << 16), a2);
        a3 = fmaf(wj, __uint_as_float(pk.y & 0xffff0000u), a3);
      }
    }
    // prefetch next group's chunk-0 col + s[col] (hides under epilogue)
    if (nxt < ngroups) {
      int nrem = pe1 - pe0;
      pc = (g < nrem) ? col[pe0 + g] : 0;
      psc = (g < nrem) ? s[pc] : 0.f;
    }
    // remaining chunks (degree > 16, ~43% of groups)
    for (int cb = 16; !__all(m - cb <= 0); cb += 16) {
      bool act = (cb + g) < m;
      int c = act ? col[e0 + cb + g] : 0;
      float w = act ? __expf(fast_tanh(srow + s[c] + be)) : 0.f;
      dl += w;
#pragma unroll
      for (int jj = 0; jj < 16; jj++) {
        int cj = __shfl(c, qb + jj, 64);
        float wj = __shfl(w, qb + jj, 64);
        uint2 pk = *(const uint2*)(v + ((size_t)cj << 6) + (g << 2));
        a0 = fmaf(wj, __uint_as_float(pk.x << 16), a0);
        a1 = fmaf(wj, __uint_as_float(pk.x & 0xffff0000u), a1);
        a2 = fmaf(wj, __uint_as_float(pk.y << 16), a2);
        a3 = fmaf(wj, __uint_as_float(pk.y & 0xffff0000u), a3);
      }
    }

    // epilogue: denom reduce (within quarter), stats, store
#pragma unroll
    for (int mm = 1; mm < 16; mm <<= 1) dl += __shfl_xor(dl, mm, 64);
    float inv = __builtin_amdgcn_rcpf(dl);
    float o0 = a0 * inv, o1 = a1 * inv, o2 = a2 * inv, o3 = a3 * inv;
    float t0 = o0 + o1 + o2 + o3;
    float t1 = o0 * o0 + o1 * o1 + o2 * o2 + o3 * o3;
#pragma unroll
    for (int mm = 1; mm < 16; mm <<= 1) {
      t0 += __shfl_xor(t0, mm, 64);
      t1 += __shfl_xor(t1, mm, 64);
    }
    float var = (t1 - t0 * t0 * (1.0f / 64.f)) * (1.0f / 63.f);
    float isd = __builtin_amdgcn_rsqf(var);
    int cnode = grp * 4 + q;
    if (cnode < n) {
      float4 r = {o0 * isd, o1 * isd, o2 * isd, o3 * isd};
      *(float4*)&out[(size_t)cnode * 64 + (g << 2)] = r;
    }
  }
}

extern "C" void kernel_launch(void* const* d_in, const int* in_sizes, int n_in,
                              void* d_out, int out_size, void* d_ws, size_t ws_size,
                              hipStream_t stream) {
  const float* h = (const float*)d_in[0];
  const int* ei = (const int*)d_in[1];
  const float* W11 = (const float*)d_in[2];
  const float* b11 = (const float*)d_in[3];
  const float* W12 = (const float*)d_in[4];  // [1,64] -> 64-vec
  const float* b12 = (const float*)d_in[5];
  const float* W13 = (const float*)d_in[6];
  const float* b13 = (const float*)d_in[7];
  const float* W21 = (const float*)d_in[8];
  const float* b21 = (const float*)d_in[9];
  const float* W22 = (const float*)d_in[10];
  const float* b22 = (const float*)d_in[11];
  const float* W23 = (const float*)d_in[12];
  const float* b23 = (const float*)d_in[13];

  const int N = in_sizes[0] / 128;  // 100000
  const int E = in_sizes[1] / 2;    // 1600000
  const int* src = ei;
  const int* dst = ei + E;
  const int NB = (N + BIN_NODES - 1) >> BIN_SHIFT;  // 782

  // workspace carve-up (~48 MB)
  char* p = (char*)d_ws;
  auto alloc = [&](size_t bytes) -> void* {
    void* r = (void*)p;
    p += (bytes + WS_ALIGN - 1) / WS_ALIGN * WS_ALIGN;
    return r;
  };
  int* cursor = (int*)alloc((size_t)NB * 4);
  int* binned = (int*)alloc((size_t)NB * BIN_CAP * 4);  // 8.0MB
  int* rsb = (int*)alloc((size_t)N * 4);
  int* reb = (int*)alloc((size_t)N * 4);
  float* sbuf = (float*)alloc((size_t)N * 4);
  unsigned short* vbuf = (unsigned short*)alloc((size_t)N * 64 * 2);  // bf16
  float* out1 = (float*)alloc((size_t)N * 64 * 4);
  short* Wh1 = (short*)alloc(128 * 128 * 2);
  short* Wl1 = (short*)alloc(128 * 128 * 2);
  short* Wh2 = (short*)alloc(128 * 64 * 2);
  short* Wl2 = (short*)alloc(128 * 64 * 2);

  const int BIN_BLKS = (E + EPB - 1) / EPB;        // 391
  const int SETUP_BLKS = 24576 / 256;              // 96
  const int NODE_BLKS = (N + NROWS - 1) / NROWS;   // 3125

  // ---- zero cursor (graph-capturable), then fused bin || weight-prep ----
  (void)hipMemsetAsync(cursor, 0, (size_t)NB * 4, stream);
  k_bin_setup<<<BIN_BLKS + SETUP_BLKS, 256, 0, stream>>>(
      src, dst, cursor, binned, E, NB, BIN_BLKS,
      W11, W13, Wh1, Wl1, W21, W23, Wh2, Wl2);

  // ---- fused k_node<128> || per-bin sort (independent) ----
  k_node128_sort<<<NODE_BLKS + NB, 256, 0, stream>>>(
      NODE_BLKS, h, Wh1, Wl1, b11, W12, b13, vbuf, sbuf, N,
      binned, cursor, rsb, reb);

  // ---- layer 1 aggregation ----
  k_aggr<<<AGGR_BLOCKS, 256, 0, stream>>>(rsb, reb, binned, sbuf, b12, vbuf, out1, N);

  // ---- layer 2 (K=64) ----
  k_node<64><<<NODE_BLKS, 256, 0, stream>>>(out1, Wh2, Wl2, b21, W22, b23, vbuf, sbuf, N);
  k_aggr<<<AGGR_BLOCKS, 256, 0, stream>>>(rsb, reb, binned, sbuf, b22, vbuf, (float*)d_out, N);
}

// Round 15
// 262.716 us; speedup vs baseline: 1.1240x; 1.0312x over previous
//
#include <hip/hip_runtime.h>

// GAT 2-layer, N=100000 nodes, E=1.6M edges, dims 128->64->64, all fp32.
// Strategy:
//   - s[i] = a[i]·we collapses edge-logit GEMV to per-node scalar (We is [1,64]).
//   - tanh-bounded logits => skip segment_max (exp ratio identical).
//   - CSR build: coarse 128-node-bin counting sort + per-bin in-LDS sort.
//     R9: within-node DETERMINISTIC order (rank-sort by dst).
//   - k_aggr v7 @2048 blocks: proven floor 42.6us (R5-R10: 5 redesigns lost).
//     ~205MB of 128B v-rows through L2/L3 is the fundamental traffic.
//   - R19/R20 fusion: memset(cursor) -> [k_bin || weight-prep] ->
//     [k_node128 || k_sort_bin] -> aggr1 -> k_node64 -> aggr2.
//   - R21/R22: node tile 64->32 rows. NULL result (48.5->48.4us, occ 31%
//     both) -> LDS residency was NOT the fused kernel's limiter.
//   - R23 (this round): the fused kernel's cost = node_phase + SORT TAIL.
//     Sort blocks (782, long: counting sort + rank pass over ~2048 entries)
//     had blockIdx AFTER 3125 node blocks -> they start only as node blocks
//     drain. SWAP ORDER: sort blocks first (start at t=0, run concurrent
//     with node stream), node blocks backfill. No arithmetic change ->
//     bitwise deterministic.

#define WS_ALIGN 256
#define BIN_SHIFT 7
#define BIN_NODES 128
#define BIN_CAP 2560   // mean bin count 2048, sigma ~44 -> +11.6 sigma margin
#define MAX_BINS 1024
#define EPB 4096       // edges per k_bin block
#define AGGR_BLOCKS 2048
#define NROWS 32       // nodes per node-transform block (R21)

typedef __attribute__((ext_vector_type(8))) short short8;
typedef __attribute__((ext_vector_type(4))) short short4_t;
typedef __attribute__((ext_vector_type(4))) float f32x4;

__device__ __forceinline__ float fast_tanh(float x) {
  x = fminf(15.f, fmaxf(-15.f, x));
  float e = __expf(2.f * x);
  return (e - 1.f) * __builtin_amdgcn_rcpf(e + 1.f);
}

__device__ __forceinline__ unsigned short f32_to_bf16_rne(float f) {
  unsigned u = __float_as_uint(f);
  unsigned r = u + 0x7fffu + ((u >> 16) & 1u);
  return (unsigned short)(r >> 16);
}

// Split one element of [Wa;Wv] into bf16 hi/lo, FRAGMENT-LINEAR layout:
// i = (((nt*KBLK + kb)*4 + q)*16 + c)*8 + j  <->  W[nt*16+c][kb*32+q*8+j].
__device__ __forceinline__ void prepw_one(const float* __restrict__ Wa,
                                          const float* __restrict__ Wv,
                                          short* __restrict__ Wh, short* __restrict__ Wl,
                                          int K, int i) {
  int KBLK = K / 32;
  int j = i & 7;
  int c = (i >> 3) & 15;
  int q = (i >> 7) & 3;
  int r = i >> 9;  // nt*KBLK + kb
  int nt = r / KBLK, kb = r - nt * KBLK;
  int row = nt * 16 + c;
  int col = kb * 32 + q * 8 + j;
  float f = (row < 64) ? Wa[row * K + col] : Wv[(row - 64) * K + col];
  unsigned u = __float_as_uint(f);
  float hf = __uint_as_float(u & 0xffff0000u);
  Wh[i] = (short)(u >> 16);
  Wl[i] = (short)(__float_as_uint(f - hf) >> 16);
}

// Fused: blocks [0, binBlks) do edge binning; blocks [binBlks, ...) do weight
// prep for both layers. Independent work -> concurrent in one dispatch.
// cnt0 must be ZEROED before launch (hipMemsetAsync).
__global__ __launch_bounds__(256) void k_bin_setup(
    const int* __restrict__ src, const int* __restrict__ dst,
    int* __restrict__ cnt0, int* __restrict__ binned, int E, int nb, int binBlks,
    const float* __restrict__ W11, const float* __restrict__ W13,
    short* __restrict__ Wh1, short* __restrict__ Wl1,
    const float* __restrict__ W21, const float* __restrict__ W23,
    short* __restrict__ Wh2, short* __restrict__ Wl2) {
  __shared__ int ssrc[EPB];
  __shared__ int sdst[EPB];
  __shared__ int hist[MAX_BINS];
  __shared__ int base[MAX_BINS];
  int t = threadIdx.x;
  if ((int)blockIdx.x >= binBlks) {
    // ---- weight-prep branch ----
    int i = ((int)blockIdx.x - binBlks) * 256 + t;
    if (i < 16384) {
      prepw_one(W11, W13, Wh1, Wl1, 128, i);
    } else if (i < 24576) {
      prepw_one(W21, W23, Wh2, Wl2, 64, i - 16384);
    }
    return;
  }
  // ---- binning branch ----
  for (int i = t; i < nb; i += 256) hist[i] = 0;
  __syncthreads();
  int e0 = (int)blockIdx.x * EPB;
  for (int i = t; i < EPB; i += 256) {
    int e = e0 + i;
    int sv = -1, dv = 0;
    if (e < E) {
      sv = src[e];
      dv = dst[e];
      atomicAdd(&hist[sv >> BIN_SHIFT], 1);
    }
    ssrc[i] = sv;
    sdst[i] = dv;
  }
  __syncthreads();
  for (int b = t; b < nb; b += 256) {
    int c = hist[b];
    base[b] = c ? (b * BIN_CAP + atomicAdd(&cnt0[b], c)) : 0;
    hist[b] = 0;
  }
  __syncthreads();
  for (int i = t; i < EPB; i += 256) {
    int sv = ssrc[i];
    if (sv >= 0) {
      int b = sv >> BIN_SHIFT;
      int r = atomicAdd(&hist[b], 1);
      int pos = base[b] + r;
      if (pos < (b + 1) * BIN_CAP)  // overflow guard (never expected to fire)
        binned[pos] = (sdst[i] << BIN_SHIFT) | (sv & (BIN_NODES - 1));
    }
  }
}

// ---- node-transform body ----
// D[node][0..127] = x[node][:] @ [Wa;Wv]^T, 16x16x32 bf16, hi/lo split.
// Block = 256 thr / 4 waves / ROWS nodes; wave w owns output n-tiles
// {2w,2w+1} (register-stationary W frags), iterates ROWS/16 node-subtiles
// from a pre-converted bf16 hi/lo LDS x-tile (+8-short pad -> free 2-way).
// Waves 0,1 produce a-dim partial s (combined via sP); waves 2,3 write v.
template <int K, int ROWS>
__device__ __forceinline__ void node_body(
    short* __restrict__ sah, short* __restrict__ sal, float* __restrict__ sP,
    int bid, const float* __restrict__ x, const short* __restrict__ Wh,
    const short* __restrict__ Wl, const float* __restrict__ ba,
    const float* __restrict__ we, const float* __restrict__ bv,
    unsigned short* __restrict__ v_out, float* __restrict__ s_out, int n) {
  constexpr int KBLK = K / 32;
  constexpr int RS = K + 8;  // shorts per LDS row (+16B pad)
  constexpr int NS = ROWS / 16;
  int t = threadIdx.x;
  int l = t & 63;
  int w = t >> 6;
  int q = l >> 4, c = l & 15;
  int node0b = bid * ROWS;

  // stage x tile: coalesced float4 read -> bf16 hi/lo split -> LDS
  {
    const float4* xg = (const float4*)(x + (size_t)node0b * K);
    constexpr int R4 = K / 4;
#pragma unroll
    for (int it = 0; it < ROWS * R4 / 256; it++) {
      int i = it * 256 + t;
      int r = i / R4, k4 = i - r * R4;
      float4 val = (node0b + r < n) ? xg[i] : (float4){0.f, 0.f, 0.f, 0.f};
      float xv[4] = {val.x, val.y, val.z, val.w};
      short4_t hi, lo;
#pragma unroll
      for (int j = 0; j < 4; j++) {
        unsigned u = __float_as_uint(xv[j]);
        hi[j] = (short)(u >> 16);
        float hf = __uint_as_float(u & 0xffff0000u);
        lo[j] = (short)(__float_as_uint(xv[j] - hf) >> 16);
      }
      *(short4_t*)&sah[r * RS + k4 * 4] = hi;
      *(short4_t*)&sal[r * RS + k4 * 4] = lo;
    }
  }

  // one-time W fragment loads (register-stationary), overlap staging wait
  const short8* WhF = (const short8*)Wh;
  const short8* WlF = (const short8*)Wl;
  short8 wfh[2][KBLK], wfl[2][KBLK];
#pragma unroll
  for (int mt = 0; mt < 2; mt++)
#pragma unroll
    for (int kb = 0; kb < KBLK; kb++) {
      size_t f = (size_t)((2 * w + mt) * KBLK + kb) * 64 + l;
      wfh[mt][kb] = WhF[f];
      wfl[mt][kb] = WlF[f];
    }
  __syncthreads();

  f32x4 acc[NS][2];
#pragma unroll
  for (int ns = 0; ns < NS; ns++)
#pragma unroll
    for (int mt = 0; mt < 2; mt++) acc[ns][mt] = (f32x4){0.f, 0.f, 0.f, 0.f};

#pragma unroll
  for (int ns = 0; ns < NS; ns++) {
#pragma unroll
    for (int kb = 0; kb < KBLK; kb++) {
      int off = (ns * 16 + c) * RS + kb * 32 + q * 8;
      short8 ah = *(const short8*)&sah[off];
      short8 al = *(const short8*)&sal[off];
#pragma unroll
      for (int mt = 0; mt < 2; mt++) {
        acc[ns][mt] = __builtin_amdgcn_mfma_f32_16x16x32_bf16(ah, wfh[mt][kb], acc[ns][mt], 0, 0, 0);
        acc[ns][mt] = __builtin_amdgcn_mfma_f32_16x16x32_bf16(ah, wfl[mt][kb], acc[ns][mt], 0, 0, 0);
        acc[ns][mt] = __builtin_amdgcn_mfma_f32_16x16x32_bf16(al, wfh[mt][kb], acc[ns][mt], 0, 0, 0);
      }
    }
  }

  // ---- epilogue ----
  if (w < 2) {
    float bav0 = ba[w * 32 + c], wev0 = we[w * 32 + c];
    float bav1 = ba[w * 32 + 16 + c], wev1 = we[w * 32 + 16 + c];
#pragma unroll
    for (int ns = 0; ns < NS; ns++) {
#pragma unroll
      for (int r = 0; r < 4; r++) {
        float pv = fast_tanh(acc[ns][0][r] + bav0) * wev0 +
                   fast_tanh(acc[ns][1][r] + bav1) * wev1;
#pragma unroll
        for (int mm = 1; mm < 16; mm <<= 1) pv += __shfl_xor(pv, mm, 64);
        if (c == 0) sP[w * ROWS + ns * 16 + q * 4 + r] = pv;
      }
    }
  } else {
    int wv = w - 2;
    float bvv0 = bv[wv * 32 + c], bvv1 = bv[wv * 32 + 16 + c];
#pragma unroll
    for (int ns = 0; ns < NS; ns++) {
#pragma unroll
      for (int r = 0; r < 4; r++) {
        int node = node0b + ns * 16 + q * 4 + r;
        if (node < n) {
          v_out[(size_t)node * 64 + wv * 32 + c] =
              f32_to_bf16_rne(fast_tanh(acc[ns][0][r] + bvv0));
          v_out[(size_t)node * 64 + wv * 32 + 16 + c] =
              f32_to_bf16_rne(fast_tanh(acc[ns][1][r] + bvv1));
        }
      }
    }
  }
  __syncthreads();
  if (t < ROWS) {
    int node = node0b + t;
    if (node < n) s_out[node] = sP[t] + sP[ROWS + t];
  }
}

// ---- per-bin sort body (counting sort + deterministic rank-sort) ----
__device__ __forceinline__ void sort_body(
    int* __restrict__ ents, int* __restrict__ sorted, int* __restrict__ hist,
    int* __restrict__ scan, int* __restrict__ cur, int bin,
    int* __restrict__ binned, const int* __restrict__ cnt0,
    int* __restrict__ rs, int* __restrict__ re, int n) {
  int t = threadIdx.x;
  int nbase = bin << BIN_SHIFT;
  int cnt = cnt0[bin];
  if (cnt > BIN_CAP) cnt = BIN_CAP;
  if (t < BIN_NODES) hist[t] = 0;
  __syncthreads();
  int* bp = binned + (size_t)bin * BIN_CAP;
  for (int i = t; i < cnt; i += 256) {
    int pk = bp[i];
    ents[i] = pk;
    atomicAdd(&hist[pk & (BIN_NODES - 1)], 1);
  }
  __syncthreads();
  if (t < BIN_NODES) scan[t] = hist[t];
  __syncthreads();
  for (int off = 1; off < BIN_NODES; off <<= 1) {
    int add = (t < BIN_NODES && t >= off) ? scan[t - off] : 0;
    __syncthreads();
    if (t < BIN_NODES) scan[t] += add;
    __syncthreads();
  }
  if (t < BIN_NODES) {
    int ex = scan[t] - hist[t];  // exclusive
    cur[t] = ex;
    int node = nbase + t;
    if (node < n) {
      rs[node] = bin * BIN_CAP + ex;
      re[node] = bin * BIN_CAP + ex + hist[t];
    }
  }
  __syncthreads();
  // scatter by node (keep full pk — needed for the rank pass)
  for (int i = t; i < cnt; i += 256) {
    int pk = ents[i];
    int pos = atomicAdd(&cur[pk & (BIN_NODES - 1)], 1);
    sorted[pos] = pk;
  }
  __syncthreads();
  // deterministic rank-sort within each node segment, ascending by dst.
  for (int i = t; i < cnt; i += 256) {
    int pk = sorted[i];
    int node = pk & (BIN_NODES - 1);
    int hi = scan[node];
    int lo = hi - hist[node];
    int r = lo;
    for (int j = lo; j < hi; j++) {
      int pj = sorted[j];
      r += (pj < pk) || (pj == pk && j < i);
    }
    ents[r] = pk >> BIN_SHIFT;  // keep dst only
  }
  __syncthreads();
  for (int i = t; i < cnt; i += 256) bp[i] = ents[i];  // coalesced write-back
}

// Fused: blocks [0, sortBlks) run the per-bin sort (LONG blocks — dispatched
// FIRST so they run concurrent with the node stream, R23); blocks
// [sortBlks, ...) run node<128,32>. LDS unioned (22.3KB).
__global__ __launch_bounds__(256) void k_node128_sort(
    int sortBlks,
    const float* __restrict__ x, const short* __restrict__ Wh,
    const short* __restrict__ Wl, const float* __restrict__ ba,
    const float* __restrict__ we, const float* __restrict__ bv,
    unsigned short* __restrict__ v_out, float* __restrict__ s_out, int n,
    int* __restrict__ binned, const int* __restrict__ cnt0,
    int* __restrict__ rs, int* __restrict__ re) {
  // node<128,32>: 2*32*136 shorts + 64 floats = 17664B ; sort: 22016B
  __shared__ __align__(16) char smem[22272];
  if ((int)blockIdx.x < sortBlks) {
    int* ents = (int*)smem;
    int* sorted = ents + BIN_CAP;
    int* hist = sorted + BIN_CAP;
    int* scan = hist + BIN_NODES;
    int* cur = scan + BIN_NODES;
    sort_body(ents, sorted, hist, scan, cur, (int)blockIdx.x,
              binned, cnt0, rs, re, n);
  } else {
    short* sah = (short*)smem;
    short* sal = (short*)(smem + NROWS * 136 * 2);
    float* sP = (float*)(smem + NROWS * 136 * 4);
    node_body<128, NROWS>(sah, sal, sP, (int)blockIdx.x - sortBlks,
                          x, Wh, Wl, ba, we, bv, v_out, s_out, n);
  }
}

// Standalone node kernel for layer 2 (K=64, 32-node blocks, 9.5KB LDS).
template <int K>
__global__ __launch_bounds__(256) void k_node(
    const float* __restrict__ x, const short* __restrict__ Wh,
    const short* __restrict__ Wl, const float* __restrict__ ba,
    const float* __restrict__ we, const float* __restrict__ bv,
    unsigned short* __restrict__ v_out, float* __restrict__ s_out, int n) {
  __shared__ short sah[NROWS * (K + 8)];
  __shared__ short sal[NROWS * (K + 8)];
  __shared__ float sP[2 * NROWS];
  node_body<K, NROWS>(sah, sal, sP, (int)blockIdx.x, x, Wh, Wl, ba, we, bv,
                      v_out, s_out, n);
}

// k_aggr v7 (proven 42.6us @2048 blocks): 4 nodes per wave, group-pipelined.
// Lane = (node-slot q=l>>4, dim-group g=l&15). Next group's (rs,re,s) issue
// before current gathers; next group's (col, s[col]) right after current
// chunk-0 gathers. Accumulation order fixed -> bitwise deterministic.
__global__ __launch_bounds__(256) void k_aggr(const int* __restrict__ rs,
                                              const int* __restrict__ re,
                                              const int* __restrict__ col,
                                              const float* __restrict__ s,
                                              const float* __restrict__ be_p,
                                              const unsigned short* __restrict__ v,
                                              float* __restrict__ out, int n) {
  int wid = (int)((blockIdx.x * 256 + threadIdx.x) >> 6);
  int nwv = (int)gridDim.x * 4;
  int l = threadIdx.x & 63;
  int q = l >> 4;  // node slot 0..3
  int g = l & 15;  // dim group: dims g*4 .. g*4+3
  int qb = l & 48; // quarter base lane
  float be = be_p[0];
  int ngroups = (n + 3) >> 2;
  if (wid >= ngroups) return;

  // prefetch meta for first group
  int pnode = wid * 4 + q;
  bool pvn = pnode < n;
  int pe0 = pvn ? rs[pnode] : 0;
  int pe1 = pvn ? re[pnode] : 0;
  float psrow = pvn ? s[pnode] : 0.f;
  int pc;
  float psc;
  {
    int prem = pe1 - pe0;
    pc = (g < prem) ? col[pe0 + g] : 0;
    psc = (g < prem) ? s[pc] : 0.f;
  }

  for (int grp = wid; grp < ngroups; grp += nwv) {
    int e0 = pe0, e1 = pe1;
    float srow = psrow;
    int c0 = pc;
    float sc0 = psc;
    int nxt = grp + nwv;
    if (nxt < ngroups) {  // issue next group's meta loads now
      int nn = nxt * 4 + q;
      bool nv = nn < n;
      pe0 = nv ? rs[nn] : 0;
      pe1 = nv ? re[nn] : 0;
      psrow = nv ? s[nn] : 0.f;
    }
    int m = e1 - e0;  // this quarter's degree
    float a0 = 0.f, a1 = 0.f, a2 = 0.f, a3 = 0.f;
    float dl = 0.f;

    // chunk 0 (col + s[col] prefetched)
    {
      float w = (g < m) ? __expf(fast_tanh(srow + sc0 + be)) : 0.f;
      dl += w;
#pragma unroll
      for (int jj = 0; jj < 16; jj++) {
        int cj = __shfl(c0, qb + jj, 64);
        float wj = __shfl(w, qb + jj, 64);
        uint2 pk = *(const uint2*)(v + ((size_t)cj << 6) + (g << 2));
        a0 = fmaf(wj, __uint_as_float(pk.x << 16), a0);
        a1 = fmaf(wj, __uint_as_float(pk.x & 0xffff0000u), a1);
        a2 = fmaf(wj, __uint_as_float(pk.y << 16), a2);
        a3 = fmaf(wj, __uint_as_float(pk.y & 0xffff0000u), a3);
      }
    }
    // prefetch next group's chunk-0 col + s[col] (hides under epilogue)
    if (nxt < ngroups) {
      int nrem = pe1 - pe0;
      pc = (g < nrem) ? col[pe0 + g] : 0;
      psc = (g < nrem) ? s[pc] : 0.f;
    }
    // remaining chunks (degree > 16, ~43% of groups)
    for (int cb = 16; !__all(m - cb <= 0); cb += 16) {
      bool act = (cb + g) < m;
      int c = act ? col[e0 + cb + g] : 0;
      float w = act ? __expf(fast_tanh(srow + s[c] + be)) : 0.f;
      dl += w;
#pragma unroll
      for (int jj = 0; jj < 16; jj++) {
        int cj = __shfl(c, qb + jj, 64);
        float wj = __shfl(w, qb + jj, 64);
        uint2 pk = *(const uint2*)(v + ((size_t)cj << 6) + (g << 2));
        a0 = fmaf(wj, __uint_as_float(pk.x << 16), a0);
        a1 = fmaf(wj, __uint_as_float(pk.x & 0xffff0000u), a1);
        a2 = fmaf(wj, __uint_as_float(pk.y << 16), a2);
        a3 = fmaf(wj, __uint_as_float(pk.y & 0xffff0000u), a3);
      }
    }

    // epilogue: denom reduce (within quarter), stats, store
#pragma unroll
    for (int mm = 1; mm < 16; mm <<= 1) dl += __shfl_xor(dl, mm, 64);
    float inv = __builtin_amdgcn_rcpf(dl);
    float o0 = a0 * inv, o1 = a1 * inv, o2 = a2 * inv, o3 = a3 * inv;
    float t0 = o0 + o1 + o2 + o3;
    float t1 = o0 * o0 + o1 * o1 + o2 * o2 + o3 * o3;
#pragma unroll
    for (int mm = 1; mm < 16; mm <<= 1) {
      t0 += __shfl_xor(t0, mm, 64);
      t1 += __shfl_xor(t1, mm, 64);
    }
    float var = (t1 - t0 * t0 * (1.0f / 64.f)) * (1.0f / 63.f);
    float isd = __builtin_amdgcn_rsqf(var);
    int cnode = grp * 4 + q;
    if (cnode < n) {
      float4 r = {o0 * isd, o1 * isd, o2 * isd, o3 * isd};
      *(float4*)&out[(size_t)cnode * 64 + (g << 2)] = r;
    }
  }
}

extern "C" void kernel_launch(void* const* d_in, const int* in_sizes, int n_in,
                              void* d_out, int out_size, void* d_ws, size_t ws_size,
                              hipStream_t stream) {
  const float* h = (const float*)d_in[0];
  const int* ei = (const int*)d_in[1];
  const float* W11 = (const float*)d_in[2];
  const float* b11 = (const float*)d_in[3];
  const float* W12 = (const float*)d_in[4];  // [1,64] -> 64-vec
  const float* b12 = (const float*)d_in[5];
  const float* W13 = (const float*)d_in[6];
  const float* b13 = (const float*)d_in[7];
  const float* W21 = (const float*)d_in[8];
  const float* b21 = (const float*)d_in[9];
  const float* W22 = (const float*)d_in[10];
  const float* b22 = (const float*)d_in[11];
  const float* W23 = (const float*)d_in[12];
  const float* b23 = (const float*)d_in[13];

  const int N = in_sizes[0] / 128;  // 100000
  const int E = in_sizes[1] / 2;    // 1600000
  const int* src = ei;
  const int* dst = ei + E;
  const int NB = (N + BIN_NODES - 1) >> BIN_SHIFT;  // 782

  // workspace carve-up (~48 MB)
  char* p = (char*)d_ws;
  auto alloc = [&](size_t bytes) -> void* {
    void* r = (void*)p;
    p += (bytes + WS_ALIGN - 1) / WS_ALIGN * WS_ALIGN;
    return r;
  };
  int* cursor = (int*)alloc((size_t)NB * 4);
  int* binned = (int*)alloc((size_t)NB * BIN_CAP * 4);  // 8.0MB
  int* rsb = (int*)alloc((size_t)N * 4);
  int* reb = (int*)alloc((size_t)N * 4);
  float* sbuf = (float*)alloc((size_t)N * 4);
  unsigned short* vbuf = (unsigned short*)alloc((size_t)N * 64 * 2);  // bf16
  float* out1 = (float*)alloc((size_t)N * 64 * 4);
  short* Wh1 = (short*)alloc(128 * 128 * 2);
  short* Wl1 = (short*)alloc(128 * 128 * 2);
  short* Wh2 = (short*)alloc(128 * 64 * 2);
  short* Wl2 = (short*)alloc(128 * 64 * 2);

  const int BIN_BLKS = (E + EPB - 1) / EPB;        // 391
  const int SETUP_BLKS = 24576 / 256;              // 96
  const int NODE_BLKS = (N + NROWS - 1) / NROWS;   // 3125

  // ---- zero cursor (graph-capturable), then fused bin || weight-prep ----
  (void)hipMemsetAsync(cursor, 0, (size_t)NB * 4, stream);
  k_bin_setup<<<BIN_BLKS + SETUP_BLKS, 256, 0, stream>>>(
      src, dst, cursor, binned, E, NB, BIN_BLKS,
      W11, W13, Wh1, Wl1, W21, W23, Wh2, Wl2);

  // ---- fused per-bin sort (first!) || k_node<128> ----
  k_node128_sort<<<NB + NODE_BLKS, 256, 0, stream>>>(
      NB, h, Wh1, Wl1, b11, W12, b13, vbuf, sbuf, N,
      binned, cursor, rsb, reb);

  // ---- layer 1 aggregation ----
  k_aggr<<<AGGR_BLOCKS, 256, 0, stream>>>(rsb, reb, binned, sbuf, b12, vbuf, out1, N);

  // ---- layer 2 (K=64) ----
  k_node<64><<<NODE_BLKS, 256, 0, stream>>>(out1, Wh2, Wl2, b21, W22, b23, vbuf, sbuf, N);
  k_aggr<<<AGGR_BLOCKS, 256, 0, stream>>>(rsb, reb, binned, sbuf, b22, vbuf, (float*)d_out, N);
}